// Round 1
// baseline (1216.529 us; speedup 1.0000x reference)
//
#include <hip/hip_runtime.h>
#include <math.h>

#define NTN 32768
#define BB 16
#define NN 2048
#define IN_CH 128
#define HC 256
#define EREAL 524288
#define ETOT (EREAL + NTN)
#define FC0 1024
#define FC1 512
#define OMIC 128
#define OUTD 2

static __device__ __forceinline__ float wave_sum(float v) {
    for (int o = 32; o; o >>= 1) v += __shfl_xor(v, o);
    return v;
}

// ---- per-node mean over IN_CH (one wave per node) ----
__global__ __launch_bounds__(256) void k_mean(const float* __restrict__ x, float* __restrict__ xmean) {
    int wave = threadIdx.x >> 6, lane = threadIdx.x & 63;
    int n = blockIdx.x * 4 + wave;
    float2 v = *(const float2*)(x + (size_t)n * IN_CH + lane * 2);
    float s = wave_sum(v.x + v.y);
    if (lane == 0) xmean[n] = s * (1.0f / 128.0f);
}

// ---- CSR build ----
__global__ void k_deg(const int* __restrict__ ei, int* __restrict__ deg) {
    int e = blockIdx.x * 256 + threadIdx.x;
    if (e < EREAL) atomicAdd(&deg[ei[EREAL + e]], 1);
}

__global__ __launch_bounds__(1024) void k_scan(const int* __restrict__ deg, int* __restrict__ rowptr,
                                               int* __restrict__ cursor) {
    __shared__ int sd[1024];
    int t = threadIdx.x;
    int base = t * 32;
    int loc[32];
    int s = 0;
    for (int j = 0; j < 32; j++) { int d = deg[base + j] + 1; loc[j] = d; s += d; }
    sd[t] = s; __syncthreads();
    for (int o = 1; o < 1024; o <<= 1) {
        int v = (t >= o) ? sd[t - o] : 0;
        __syncthreads();
        sd[t] += v;
        __syncthreads();
    }
    int run = sd[t] - s;  // exclusive prefix
    for (int j = 0; j < 32; j++) { rowptr[base + j] = run; cursor[base + j] = run; run += loc[j]; }
    if (t == 1023) rowptr[NTN] = run;
}

__global__ void k_fill(const int* __restrict__ ei, int* __restrict__ cursor, int* __restrict__ csr) {
    int e = blockIdx.x * 256 + threadIdx.x;
    if (e >= ETOT) return;
    int s, d;
    if (e < EREAL) { s = ei[e]; d = ei[EREAL + e]; } else { s = d = e - EREAL; }
    int pos = atomicAdd(&cursor[d], 1);
    csr[pos] = s;
}

// ---- fp32 GEMM  C[M,256] = A[M,K] @ W[K,256], fused a_src/a_dst head dots ----
// grid: (4, M/64); block 256; 64x64 tile, 4x4 per thread. col-block bx == head bx.
__global__ __launch_bounds__(256) void k_gemm_att(
    const float* __restrict__ A, const float* __restrict__ W, int K,
    const float* __restrict__ attS, const float* __restrict__ attD,
    float* __restrict__ Cout, float* __restrict__ aS, float* __restrict__ aD) {
    __shared__ float As[16][68];   // [k][row], padded
    __shared__ float Ws[16][68];   // [k][col], padded
    const int t = threadIdx.x;
    const int tx = t & 15, ty = t >> 4;
    const int bx = blockIdx.x, by = blockIdx.y;
    const int lrow = t >> 2, lkg = t & 3;   // A tile load: row, k-group
    const int wk = t >> 4, wcg = t & 15;    // W tile load: k, col-group
    const float* Aload = A + (size_t)(by * 64 + lrow) * K + lkg * 4;
    const float* Wload = W + (size_t)wk * HC + bx * 64 + wcg * 4;
    float acc[4][4] = {};
    for (int k0 = 0; k0 < K; k0 += 16) {
        float4 a4 = *(const float4*)(Aload + k0);
        float4 w4 = *(const float4*)(Wload + (size_t)k0 * HC);
        __syncthreads();
        As[lkg * 4 + 0][lrow] = a4.x;
        As[lkg * 4 + 1][lrow] = a4.y;
        As[lkg * 4 + 2][lrow] = a4.z;
        As[lkg * 4 + 3][lrow] = a4.w;
        *(float4*)&Ws[wk][wcg * 4] = w4;
        __syncthreads();
#pragma unroll
        for (int kk = 0; kk < 16; kk++) {
            float4 av = *(const float4*)&As[kk][ty * 4];
            float4 bv = *(const float4*)&Ws[kk][tx * 4];
            acc[0][0] += av.x * bv.x; acc[0][1] += av.x * bv.y; acc[0][2] += av.x * bv.z; acc[0][3] += av.x * bv.w;
            acc[1][0] += av.y * bv.x; acc[1][1] += av.y * bv.y; acc[1][2] += av.y * bv.z; acc[1][3] += av.y * bv.w;
            acc[2][0] += av.z * bv.x; acc[2][1] += av.z * bv.y; acc[2][2] += av.z * bv.z; acc[2][3] += av.z * bv.w;
            acc[3][0] += av.w * bv.x; acc[3][1] += av.w * bv.y; acc[3][2] += av.w * bv.z; acc[3][3] += av.w * bv.w;
        }
    }
    float as_c[4], ad_c[4];
#pragma unroll
    for (int c = 0; c < 4; c++) {
        as_c[c] = attS[bx * 64 + tx * 4 + c];
        ad_c[c] = attD[bx * 64 + tx * 4 + c];
    }
#pragma unroll
    for (int r = 0; r < 4; r++) {
        int row = by * 64 + ty * 4 + r;
        float4 v;
        v.x = acc[r][0]; v.y = acc[r][1]; v.z = acc[r][2]; v.w = acc[r][3];
        *(float4*)&Cout[(size_t)row * HC + bx * 64 + tx * 4] = v;
        float ps = acc[r][0] * as_c[0] + acc[r][1] * as_c[1] + acc[r][2] * as_c[2] + acc[r][3] * as_c[3];
        float pd = acc[r][0] * ad_c[0] + acc[r][1] * ad_c[1] + acc[r][2] * ad_c[2] + acc[r][3] * ad_c[3];
        for (int o = 8; o; o >>= 1) { ps += __shfl_xor(ps, o); pd += __shfl_xor(pd, o); }
        if (tx == 0) { aS[row * 4 + bx] = ps; aD[row * 4 + bx] = pd; }
    }
}

// ---- attention softmax + aggregate + bias + ELU + pool (one wave per node) ----
__global__ __launch_bounds__(256) void k_agg(
    const float* __restrict__ xw, const float* __restrict__ aS, const float* __restrict__ aD,
    const int* __restrict__ rowptr, const int* __restrict__ csr,
    const float* __restrict__ bias, const float* __restrict__ poolw, const float* __restrict__ poolb,
    float* __restrict__ hout, float* __restrict__ xpre) {
    int wave = threadIdx.x >> 6, lane = threadIdx.x & 63;
    int n = blockIdx.x * 4 + wave;
    int beg = rowptr[n], end = rowptr[n + 1];
    float4 ad4 = *(const float4*)(aD + n * 4);
    float m[4] = {-INFINITY, -INFINITY, -INFINITY, -INFINITY};
    for (int i = beg + lane; i < end; i += 64) {
        int s = csr[i];
        float4 as4 = *(const float4*)(aS + s * 4);
        float a0 = as4.x + ad4.x; a0 = a0 > 0.f ? a0 : 0.2f * a0; m[0] = fmaxf(m[0], a0);
        float a1 = as4.y + ad4.y; a1 = a1 > 0.f ? a1 : 0.2f * a1; m[1] = fmaxf(m[1], a1);
        float a2 = as4.z + ad4.z; a2 = a2 > 0.f ? a2 : 0.2f * a2; m[2] = fmaxf(m[2], a2);
        float a3 = as4.w + ad4.w; a3 = a3 > 0.f ? a3 : 0.2f * a3; m[3] = fmaxf(m[3], a3);
    }
#pragma unroll
    for (int h = 0; h < 4; h++)
        for (int o = 32; o; o >>= 1) m[h] = fmaxf(m[h], __shfl_xor(m[h], o));
    float l[4] = {0.f, 0.f, 0.f, 0.f};
    for (int i = beg + lane; i < end; i += 64) {
        int s = csr[i];
        float4 as4 = *(const float4*)(aS + s * 4);
        float a0 = as4.x + ad4.x; a0 = a0 > 0.f ? a0 : 0.2f * a0; l[0] += expf(a0 - m[0]);
        float a1 = as4.y + ad4.y; a1 = a1 > 0.f ? a1 : 0.2f * a1; l[1] += expf(a1 - m[1]);
        float a2 = as4.z + ad4.z; a2 = a2 > 0.f ? a2 : 0.2f * a2; l[2] += expf(a2 - m[2]);
        float a3 = as4.w + ad4.w; a3 = a3 > 0.f ? a3 : 0.2f * a3; l[3] += expf(a3 - m[3]);
    }
    float invl[4];
#pragma unroll
    for (int h = 0; h < 4; h++) { l[h] = wave_sum(l[h]); invl[h] = 1.0f / (l[h] + 1e-16f); }
    int hd = lane >> 4;
    float mh = m[hd], il = invl[hd];
    float adh = (hd == 0) ? ad4.x : (hd == 1) ? ad4.y : (hd == 2) ? ad4.z : ad4.w;
    float4 acc = {0.f, 0.f, 0.f, 0.f};
    for (int i = beg; i < end; i++) {
        int s = csr[i];
        float a = aS[s * 4 + hd] + adh;
        a = a > 0.f ? a : 0.2f * a;
        float coef = expf(a - mh) * il;
        float4 v = *(const float4*)(xw + (size_t)s * HC + lane * 4);
        acc.x += v.x * coef; acc.y += v.y * coef; acc.z += v.z * coef; acc.w += v.w * coef;
    }
    float4 bv = *(const float4*)(bias + lane * 4);
    float4 r;
    r.x = acc.x + bv.x; r.x = r.x > 0.f ? r.x : expm1f(r.x);
    r.y = acc.y + bv.y; r.y = r.y > 0.f ? r.y : expm1f(r.y);
    r.z = acc.z + bv.z; r.z = r.z > 0.f ? r.z : expm1f(r.z);
    r.w = acc.w + bv.w; r.w = r.w > 0.f ? r.w : expm1f(r.w);
    if (hout) *(float4*)(hout + (size_t)n * HC + lane * 4) = r;
    float4 pw = *(const float4*)(poolw + lane * 4);
    float p = r.x * pw.x + r.y * pw.y + r.z * pw.z + r.w * pw.w;
    p = wave_sum(p);
    if (lane == 0) xpre[n] = p + poolb[0];
}

// ---- LayerNorm over rows of [B, NN]; dst already offset to the feat column block ----
__global__ __launch_bounds__(256) void k_ln(const float* __restrict__ src, const float* __restrict__ lw,
                                            const float* __restrict__ lb, float* __restrict__ dst) {
    __shared__ float r0[256], r1[256];
    int row = blockIdx.x, t = threadIdx.x;
    float v[8];
    float s = 0.f, s2 = 0.f;
#pragma unroll
    for (int j = 0; j < 8; j++) {
        float x = src[(size_t)row * NN + t + j * 256];
        v[j] = x; s += x; s2 += x * x;
    }
    r0[t] = s; r1[t] = s2; __syncthreads();
    for (int o = 128; o; o >>= 1) {
        if (t < o) { r0[t] += r0[t + o]; r1[t] += r1[t + o]; }
        __syncthreads();
    }
    float mu = r0[0] * (1.0f / NN);
    float var = r1[0] * (1.0f / NN) - mu * mu;
    float rs = rsqrtf(var + 1e-5f);
#pragma unroll
    for (int j = 0; j < 8; j++) {
        int idx = t + j * 256;
        dst[(size_t)row * (3 * NN) + idx] = (v[j] - mu) * rs * lw[idx] + lb[idx];
    }
}

// ---- small FC: Out[16,Nc] = act(In[16,K] @ W[K,Nc] + b) ----
__global__ __launch_bounds__(256) void k_fc(const float* __restrict__ In, const float* __restrict__ W,
                                            const float* __restrict__ bias, float* __restrict__ Out,
                                            int K, int Nc, int doElu) {
    __shared__ float in_s[16][68];
    int t = threadIdx.x;
    int col = blockIdx.x * 64 + (t & 63);
    int rg = t >> 6;
    int lr = t >> 4, lc = t & 15;
    float acc[4] = {0.f, 0.f, 0.f, 0.f};
    for (int k0 = 0; k0 < K; k0 += 64) {
        __syncthreads();
        *(float4*)&in_s[lr][lc * 4] = *(const float4*)(In + (size_t)lr * K + k0 + lc * 4);
        __syncthreads();
        if (col < Nc) {
            for (int kk = 0; kk < 64; kk++) {
                float w = W[(size_t)(k0 + kk) * Nc + col];
#pragma unroll
                for (int r = 0; r < 4; r++) acc[r] += in_s[rg * 4 + r][kk] * w;
            }
        }
    }
    if (col < Nc) {
        float bb = bias[col];
#pragma unroll
        for (int r = 0; r < 4; r++) {
            float o = acc[r] + bb;
            if (doElu) o = o > 0.f ? o : expm1f(o);
            Out[(size_t)(rg * 4 + r) * Nc + col] = o;
        }
    }
}

extern "C" void kernel_launch(void* const* d_in, const int* in_sizes, int n_in,
                              void* d_out, int out_size, void* d_ws, size_t ws_size,
                              hipStream_t stream) {
    (void)in_sizes; (void)n_in; (void)out_size; (void)ws_size;
    const float* x        = (const float*)d_in[0];
    const int*   ei       = (const int*)d_in[1];
    const float* w1       = (const float*)d_in[2];
    const float* att_src1 = (const float*)d_in[3];
    const float* att_dst1 = (const float*)d_in[4];
    const float* bias1    = (const float*)d_in[5];
    const float* pool1_w  = (const float*)d_in[6];
    const float* pool1_b  = (const float*)d_in[7];
    const float* w2       = (const float*)d_in[8];
    const float* att_src2 = (const float*)d_in[9];
    const float* att_dst2 = (const float*)d_in[10];
    const float* bias2    = (const float*)d_in[11];
    const float* pool2_w  = (const float*)d_in[12];
    const float* pool2_b  = (const float*)d_in[13];
    const float* ln_w     = (const float*)d_in[14];
    const float* ln_b     = (const float*)d_in[15];
    const float* enc0_w   = (const float*)d_in[16];
    const float* enc0_b   = (const float*)d_in[17];
    const float* enc1_w   = (const float*)d_in[18];
    const float* enc1_b   = (const float*)d_in[19];
    const float* enc2_w   = (const float*)d_in[20];
    const float* enc2_b   = (const float*)d_in[21];
    const float* last_w   = (const float*)d_in[22];
    const float* last_b   = (const float*)d_in[23];
    float* out = (float*)d_out;

    char* p = (char*)d_ws;
    auto alloc = [&](size_t bytes) -> void* {
        void* r = (void*)p;
        p += (bytes + 255) & ~(size_t)255;
        return r;
    };
    float* xw     = (float*)alloc((size_t)NTN * HC * 4);
    float* hbuf   = (float*)alloc((size_t)NTN * HC * 4);
    float* a_src  = (float*)alloc((size_t)NTN * 4 * 4);
    float* a_dst  = (float*)alloc((size_t)NTN * 4 * 4);
    float* xmean  = (float*)alloc((size_t)NTN * 4);
    float* x1pre  = (float*)alloc((size_t)NTN * 4);
    float* x2pre  = (float*)alloc((size_t)NTN * 4);
    float* feat   = (float*)alloc((size_t)BB * 3 * NN * 4);
    float* e0     = (float*)alloc((size_t)BB * FC0 * 4);
    float* e1     = (float*)alloc((size_t)BB * FC1 * 4);
    float* e2     = (float*)alloc((size_t)BB * OMIC * 4);
    int*   deg    = (int*)alloc((size_t)NTN * 4);
    int*   rowptr = (int*)alloc((size_t)(NTN + 1) * 4);
    int*   cursor = (int*)alloc((size_t)NTN * 4);
    int*   csr    = (int*)alloc((size_t)ETOT * 4);

    hipMemsetAsync(deg, 0, (size_t)NTN * 4, stream);

    k_mean<<<NTN / 4, 256, 0, stream>>>(x, xmean);
    k_deg<<<(EREAL + 255) / 256, 256, 0, stream>>>(ei, deg);
    k_scan<<<1, 1024, 0, stream>>>(deg, rowptr, cursor);
    k_fill<<<(ETOT + 255) / 256, 256, 0, stream>>>(ei, cursor, csr);

    // GAT layer 1
    k_gemm_att<<<dim3(4, NTN / 64), 256, 0, stream>>>(x, w1, IN_CH, att_src1, att_dst1, xw, a_src, a_dst);
    k_ln<<<BB, 256, 0, stream>>>(xmean, ln_w, ln_b, feat + 0);
    k_agg<<<NTN / 4, 256, 0, stream>>>(xw, a_src, a_dst, rowptr, csr, bias1, pool1_w, pool1_b, hbuf, x1pre);
    k_ln<<<BB, 256, 0, stream>>>(x1pre, ln_w, ln_b, feat + NN);

    // GAT layer 2
    k_gemm_att<<<dim3(4, NTN / 64), 256, 0, stream>>>(hbuf, w2, HC, att_src2, att_dst2, xw, a_src, a_dst);
    k_agg<<<NTN / 4, 256, 0, stream>>>(xw, a_src, a_dst, rowptr, csr, bias2, pool2_w, pool2_b, (float*)nullptr, x2pre);
    k_ln<<<BB, 256, 0, stream>>>(x2pre, ln_w, ln_b, feat + 2 * NN);

    // encoder MLP
    k_fc<<<(FC0 + 63) / 64, 256, 0, stream>>>(feat, enc0_w, enc0_b, e0, 3 * NN, FC0, 1);
    k_fc<<<(FC1 + 63) / 64, 256, 0, stream>>>(e0, enc1_w, enc1_b, e1, FC0, FC1, 1);
    k_fc<<<(OMIC + 63) / 64, 256, 0, stream>>>(e1, enc2_w, enc2_b, e2, FC1, OMIC, 1);
    k_fc<<<1, 256, 0, stream>>>(e2, last_w, last_b, out, OMIC, OUTD, 0);
}

// Round 2
// 628.833 us; speedup vs baseline: 1.9346x; 1.9346x over previous
//
#include <hip/hip_runtime.h>
#include <math.h>

#define NTN 32768
#define BB 16
#define NN 2048
#define IN_CH 128
#define HC 256
#define EREAL 524288
#define ETOT (EREAL + NTN)
#define FC0 1024
#define FC1 512
#define OMIC 128
#define OUTD 2

static __device__ __forceinline__ float wave_sum(float v) {
    for (int o = 32; o; o >>= 1) v += __shfl_xor(v, o);
    return v;
}

// ---- per-node mean over IN_CH (one wave per node) ----
__global__ __launch_bounds__(256) void k_mean(const float* __restrict__ x, float* __restrict__ xmean) {
    int wave = threadIdx.x >> 6, lane = threadIdx.x & 63;
    int n = blockIdx.x * 4 + wave;
    float2 v = *(const float2*)(x + (size_t)n * IN_CH + lane * 2);
    float s = wave_sum(v.x + v.y);
    if (lane == 0) xmean[n] = s * (1.0f / 128.0f);
}

// ---- CSR build ----
__global__ void k_deg(const int* __restrict__ ei, int* __restrict__ deg) {
    int e = blockIdx.x * 256 + threadIdx.x;
    if (e < EREAL) atomicAdd(&deg[ei[EREAL + e]], 1);
}

__global__ __launch_bounds__(1024) void k_scan(const int* __restrict__ deg, int* __restrict__ rowptr,
                                               int* __restrict__ cursor) {
    __shared__ int sd[1024];
    int t = threadIdx.x;
    int base = t * 32;
    int loc[32];
    int s = 0;
    for (int j = 0; j < 32; j++) { int d = deg[base + j] + 1; loc[j] = d; s += d; }
    sd[t] = s; __syncthreads();
    for (int o = 1; o < 1024; o <<= 1) {
        int v = (t >= o) ? sd[t - o] : 0;
        __syncthreads();
        sd[t] += v;
        __syncthreads();
    }
    int run = sd[t] - s;  // exclusive prefix
    for (int j = 0; j < 32; j++) { rowptr[base + j] = run; cursor[base + j] = run; run += loc[j]; }
    if (t == 1023) rowptr[NTN] = run;
}

__global__ void k_fill(const int* __restrict__ ei, int* __restrict__ cursor, int* __restrict__ csr) {
    int e = blockIdx.x * 256 + threadIdx.x;
    if (e >= ETOT) return;
    int s, d;
    if (e < EREAL) { s = ei[e]; d = ei[EREAL + e]; } else { s = d = e - EREAL; }
    int pos = atomicAdd(&cursor[d], 1);
    csr[pos] = s;
}

// ---- fp32 GEMM  C[M,256] = A[M,K] @ W[K,256], fused a_src/a_dst head dots ----
__global__ __launch_bounds__(256) void k_gemm_att(
    const float* __restrict__ A, const float* __restrict__ W, int K,
    const float* __restrict__ attS, const float* __restrict__ attD,
    float* __restrict__ Cout, float* __restrict__ aS, float* __restrict__ aD) {
    __shared__ float As[16][68];   // [k][row], padded
    __shared__ float Ws[16][68];   // [k][col], padded
    const int t = threadIdx.x;
    const int tx = t & 15, ty = t >> 4;
    const int bx = blockIdx.x, by = blockIdx.y;
    const int lrow = t >> 2, lkg = t & 3;   // A tile load: row, k-group
    const int wk = t >> 4, wcg = t & 15;    // W tile load: k, col-group
    const float* Aload = A + (size_t)(by * 64 + lrow) * K + lkg * 4;
    const float* Wload = W + (size_t)wk * HC + bx * 64 + wcg * 4;
    float acc[4][4] = {};
    for (int k0 = 0; k0 < K; k0 += 16) {
        float4 a4 = *(const float4*)(Aload + k0);
        float4 w4 = *(const float4*)(Wload + (size_t)k0 * HC);
        __syncthreads();
        As[lkg * 4 + 0][lrow] = a4.x;
        As[lkg * 4 + 1][lrow] = a4.y;
        As[lkg * 4 + 2][lrow] = a4.z;
        As[lkg * 4 + 3][lrow] = a4.w;
        *(float4*)&Ws[wk][wcg * 4] = w4;
        __syncthreads();
#pragma unroll
        for (int kk = 0; kk < 16; kk++) {
            float4 av = *(const float4*)&As[kk][ty * 4];
            float4 bv = *(const float4*)&Ws[kk][tx * 4];
            acc[0][0] += av.x * bv.x; acc[0][1] += av.x * bv.y; acc[0][2] += av.x * bv.z; acc[0][3] += av.x * bv.w;
            acc[1][0] += av.y * bv.x; acc[1][1] += av.y * bv.y; acc[1][2] += av.y * bv.z; acc[1][3] += av.y * bv.w;
            acc[2][0] += av.z * bv.x; acc[2][1] += av.z * bv.y; acc[2][2] += av.z * bv.z; acc[2][3] += av.z * bv.w;
            acc[3][0] += av.w * bv.x; acc[3][1] += av.w * bv.y; acc[3][2] += av.w * bv.z; acc[3][3] += av.w * bv.w;
        }
    }
    float as_c[4], ad_c[4];
#pragma unroll
    for (int c = 0; c < 4; c++) {
        as_c[c] = attS[bx * 64 + tx * 4 + c];
        ad_c[c] = attD[bx * 64 + tx * 4 + c];
    }
#pragma unroll
    for (int r = 0; r < 4; r++) {
        int row = by * 64 + ty * 4 + r;
        float4 v;
        v.x = acc[r][0]; v.y = acc[r][1]; v.z = acc[r][2]; v.w = acc[r][3];
        *(float4*)&Cout[(size_t)row * HC + bx * 64 + tx * 4] = v;
        float ps = acc[r][0] * as_c[0] + acc[r][1] * as_c[1] + acc[r][2] * as_c[2] + acc[r][3] * as_c[3];
        float pd = acc[r][0] * ad_c[0] + acc[r][1] * ad_c[1] + acc[r][2] * ad_c[2] + acc[r][3] * ad_c[3];
        for (int o = 8; o; o >>= 1) { ps += __shfl_xor(ps, o); pd += __shfl_xor(pd, o); }
        if (tx == 0) { aS[row * 4 + bx] = ps; aD[row * 4 + bx] = pd; }
    }
}

// ---- attention softmax + aggregate + bias + ELU + pool (one wave per node) ----
__global__ __launch_bounds__(256) void k_agg(
    const float* __restrict__ xw, const float* __restrict__ aS, const float* __restrict__ aD,
    const int* __restrict__ rowptr, const int* __restrict__ csr,
    const float* __restrict__ bias, const float* __restrict__ poolw, const float* __restrict__ poolb,
    float* __restrict__ hout, float* __restrict__ xpre) {
    int wave = threadIdx.x >> 6, lane = threadIdx.x & 63;
    int n = blockIdx.x * 4 + wave;
    int beg = rowptr[n], end = rowptr[n + 1];
    float4 ad4 = *(const float4*)(aD + n * 4);
    float m[4] = {-INFINITY, -INFINITY, -INFINITY, -INFINITY};
    for (int i = beg + lane; i < end; i += 64) {
        int s = csr[i];
        float4 as4 = *(const float4*)(aS + s * 4);
        float a0 = as4.x + ad4.x; a0 = a0 > 0.f ? a0 : 0.2f * a0; m[0] = fmaxf(m[0], a0);
        float a1 = as4.y + ad4.y; a1 = a1 > 0.f ? a1 : 0.2f * a1; m[1] = fmaxf(m[1], a1);
        float a2 = as4.z + ad4.z; a2 = a2 > 0.f ? a2 : 0.2f * a2; m[2] = fmaxf(m[2], a2);
        float a3 = as4.w + ad4.w; a3 = a3 > 0.f ? a3 : 0.2f * a3; m[3] = fmaxf(m[3], a3);
    }
#pragma unroll
    for (int h = 0; h < 4; h++)
        for (int o = 32; o; o >>= 1) m[h] = fmaxf(m[h], __shfl_xor(m[h], o));
    float l[4] = {0.f, 0.f, 0.f, 0.f};
    for (int i = beg + lane; i < end; i += 64) {
        int s = csr[i];
        float4 as4 = *(const float4*)(aS + s * 4);
        float a0 = as4.x + ad4.x; a0 = a0 > 0.f ? a0 : 0.2f * a0; l[0] += expf(a0 - m[0]);
        float a1 = as4.y + ad4.y; a1 = a1 > 0.f ? a1 : 0.2f * a1; l[1] += expf(a1 - m[1]);
        float a2 = as4.z + ad4.z; a2 = a2 > 0.f ? a2 : 0.2f * a2; l[2] += expf(a2 - m[2]);
        float a3 = as4.w + ad4.w; a3 = a3 > 0.f ? a3 : 0.2f * a3; l[3] += expf(a3 - m[3]);
    }
    float invl[4];
#pragma unroll
    for (int h = 0; h < 4; h++) { l[h] = wave_sum(l[h]); invl[h] = 1.0f / (l[h] + 1e-16f); }
    int hd = lane >> 4;
    float mh = m[hd], il = invl[hd];
    float adh = (hd == 0) ? ad4.x : (hd == 1) ? ad4.y : (hd == 2) ? ad4.z : ad4.w;
    float4 acc = {0.f, 0.f, 0.f, 0.f};
    for (int i = beg; i < end; i++) {
        int s = csr[i];
        float a = aS[s * 4 + hd] + adh;
        a = a > 0.f ? a : 0.2f * a;
        float coef = expf(a - mh) * il;
        float4 v = *(const float4*)(xw + (size_t)s * HC + lane * 4);
        acc.x += v.x * coef; acc.y += v.y * coef; acc.z += v.z * coef; acc.w += v.w * coef;
    }
    float4 bv = *(const float4*)(bias + lane * 4);
    float4 r;
    r.x = acc.x + bv.x; r.x = r.x > 0.f ? r.x : expm1f(r.x);
    r.y = acc.y + bv.y; r.y = r.y > 0.f ? r.y : expm1f(r.y);
    r.z = acc.z + bv.z; r.z = r.z > 0.f ? r.z : expm1f(r.z);
    r.w = acc.w + bv.w; r.w = r.w > 0.f ? r.w : expm1f(r.w);
    if (hout) *(float4*)(hout + (size_t)n * HC + lane * 4) = r;
    float4 pw = *(const float4*)(poolw + lane * 4);
    float p = r.x * pw.x + r.y * pw.y + r.z * pw.z + r.w * pw.w;
    p = wave_sum(p);
    if (lane == 0) xpre[n] = p + poolb[0];
}

// ---- LayerNorm over rows of [B, NN]; dst already offset to the feat column block ----
__global__ __launch_bounds__(256) void k_ln(const float* __restrict__ src, const float* __restrict__ lw,
                                            const float* __restrict__ lb, float* __restrict__ dst) {
    __shared__ float r0[256], r1[256];
    int row = blockIdx.x, t = threadIdx.x;
    float v[8];
    float s = 0.f, s2 = 0.f;
#pragma unroll
    for (int j = 0; j < 8; j++) {
        float x = src[(size_t)row * NN + t + j * 256];
        v[j] = x; s += x; s2 += x * x;
    }
    r0[t] = s; r1[t] = s2; __syncthreads();
    for (int o = 128; o; o >>= 1) {
        if (t < o) { r0[t] += r0[t + o]; r1[t] += r1[t + o]; }
        __syncthreads();
    }
    float mu = r0[0] * (1.0f / NN);
    float var = r1[0] * (1.0f / NN) - mu * mu;
    float rs = rsqrtf(var + 1e-5f);
#pragma unroll
    for (int j = 0; j < 8; j++) {
        int idx = t + j * 256;
        dst[(size_t)row * (3 * NN) + idx] = (v[j] - mu) * rs * lw[idx] + lb[idx];
    }
}

// ---- split-K FC stage 1: partial[ks][16][Nc] = In[16, kchunk] @ W[kchunk, Nc] ----
// grid (ceil(Nc/256), KS), block 256. In[r*K+k] is wave-uniform -> scalar loads.
__global__ __launch_bounds__(256) void k_fc_splitk(const float* __restrict__ In, const float* __restrict__ W,
                                                   float* __restrict__ partial, int K, int Nc, int KC) {
    int col = blockIdx.x * 256 + threadIdx.x;
    int k0 = blockIdx.y * KC;
    float acc[16] = {};
    if (col < Nc) {
        const float* wp = W + (size_t)k0 * Nc + col;
#pragma unroll 4
        for (int kk = 0; kk < KC; kk++) {
            float w = wp[(size_t)kk * Nc];
#pragma unroll
            for (int r = 0; r < 16; r++) acc[r] += In[r * K + k0 + kk] * w;
        }
        float* pp = partial + ((size_t)blockIdx.y * 16) * Nc + col;
#pragma unroll
        for (int r = 0; r < 16; r++) pp[(size_t)r * Nc] = acc[r];
    }
}

// ---- split-K FC stage 2: Out[16,Nc] = act(sum_ks partial + bias) ----
__global__ __launch_bounds__(256) void k_fc_reduce(const float* __restrict__ partial, const float* __restrict__ bias,
                                                   float* __restrict__ Out, int Nc, int KS, int doElu) {
    int idx = blockIdx.x * 256 + threadIdx.x;
    if (idx >= 16 * Nc) return;
    int col = idx % Nc;
    float s = bias[col];
    for (int ks = 0; ks < KS; ks++) s += partial[(size_t)ks * 16 * Nc + idx];
    if (doElu) s = s > 0.f ? s : expm1f(s);
    Out[idx] = s;
}

// ---- last layer: Out[16,2] = In[16,128] @ W[128,2] + b ----
__global__ __launch_bounds__(256) void k_last(const float* __restrict__ In, const float* __restrict__ W,
                                              const float* __restrict__ b, float* __restrict__ Out) {
    int t = threadIdx.x;
    int r = t >> 4, c = (t >> 3) & 1, ksub = t & 7;
    float s = 0.f;
    for (int k = ksub; k < OMIC; k += 8) s += In[r * OMIC + k] * W[k * OUTD + c];
    for (int o = 1; o < 8; o <<= 1) s += __shfl_xor(s, o);
    if (ksub == 0) Out[r * OUTD + c] = s + b[c];
}

extern "C" void kernel_launch(void* const* d_in, const int* in_sizes, int n_in,
                              void* d_out, int out_size, void* d_ws, size_t ws_size,
                              hipStream_t stream) {
    (void)in_sizes; (void)n_in; (void)out_size; (void)ws_size;
    const float* x        = (const float*)d_in[0];
    const int*   ei       = (const int*)d_in[1];
    const float* w1       = (const float*)d_in[2];
    const float* att_src1 = (const float*)d_in[3];
    const float* att_dst1 = (const float*)d_in[4];
    const float* bias1    = (const float*)d_in[5];
    const float* pool1_w  = (const float*)d_in[6];
    const float* pool1_b  = (const float*)d_in[7];
    const float* w2       = (const float*)d_in[8];
    const float* att_src2 = (const float*)d_in[9];
    const float* att_dst2 = (const float*)d_in[10];
    const float* bias2    = (const float*)d_in[11];
    const float* pool2_w  = (const float*)d_in[12];
    const float* pool2_b  = (const float*)d_in[13];
    const float* ln_w     = (const float*)d_in[14];
    const float* ln_b     = (const float*)d_in[15];
    const float* enc0_w   = (const float*)d_in[16];
    const float* enc0_b   = (const float*)d_in[17];
    const float* enc1_w   = (const float*)d_in[18];
    const float* enc1_b   = (const float*)d_in[19];
    const float* enc2_w   = (const float*)d_in[20];
    const float* enc2_b   = (const float*)d_in[21];
    const float* last_w   = (const float*)d_in[22];
    const float* last_b   = (const float*)d_in[23];
    float* out = (float*)d_out;

    char* p = (char*)d_ws;
    auto alloc = [&](size_t bytes) -> void* {
        void* r = (void*)p;
        p += (bytes + 255) & ~(size_t)255;
        return r;
    };
    float* xw     = (float*)alloc((size_t)NTN * HC * 4);
    float* hbuf   = (float*)alloc((size_t)NTN * HC * 4);
    float* a_src  = (float*)alloc((size_t)NTN * 4 * 4);
    float* a_dst  = (float*)alloc((size_t)NTN * 4 * 4);
    float* xmean  = (float*)alloc((size_t)NTN * 4);
    float* x1pre  = (float*)alloc((size_t)NTN * 4);
    float* x2pre  = (float*)alloc((size_t)NTN * 4);
    float* feat   = (float*)alloc((size_t)BB * 3 * NN * 4);
    float* e0     = (float*)alloc((size_t)BB * FC0 * 4);
    float* e1     = (float*)alloc((size_t)BB * FC1 * 4);
    float* e2     = (float*)alloc((size_t)BB * OMIC * 4);
    int*   deg    = (int*)alloc((size_t)NTN * 4);
    int*   rowptr = (int*)alloc((size_t)(NTN + 1) * 4);
    int*   cursor = (int*)alloc((size_t)NTN * 4);
    int*   csr    = (int*)alloc((size_t)ETOT * 4);
    // partials for split-K FC alias xw (dead after the last k_agg; max 6.3 MB << 33.5 MB)
    float* partial = xw;

    hipMemsetAsync(deg, 0, (size_t)NTN * 4, stream);

    k_mean<<<NTN / 4, 256, 0, stream>>>(x, xmean);
    k_deg<<<(EREAL + 255) / 256, 256, 0, stream>>>(ei, deg);
    k_scan<<<1, 1024, 0, stream>>>(deg, rowptr, cursor);
    k_fill<<<(ETOT + 255) / 256, 256, 0, stream>>>(ei, cursor, csr);

    // GAT layer 1
    k_gemm_att<<<dim3(4, NTN / 64), 256, 0, stream>>>(x, w1, IN_CH, att_src1, att_dst1, xw, a_src, a_dst);
    k_ln<<<BB, 256, 0, stream>>>(xmean, ln_w, ln_b, feat + 0);
    k_agg<<<NTN / 4, 256, 0, stream>>>(xw, a_src, a_dst, rowptr, csr, bias1, pool1_w, pool1_b, hbuf, x1pre);
    k_ln<<<BB, 256, 0, stream>>>(x1pre, ln_w, ln_b, feat + NN);

    // GAT layer 2
    k_gemm_att<<<dim3(4, NTN / 64), 256, 0, stream>>>(hbuf, w2, HC, att_src2, att_dst2, xw, a_src, a_dst);
    k_agg<<<NTN / 4, 256, 0, stream>>>(xw, a_src, a_dst, rowptr, csr, bias2, pool2_w, pool2_b, (float*)nullptr, x2pre);
    k_ln<<<BB, 256, 0, stream>>>(x2pre, ln_w, ln_b, feat + 2 * NN);

    // encoder MLP (split-K): enc0 K=6144 KS=96 KC=64; enc1 K=1024 KS=64 KC=16; enc2 K=512 KS=32 KC=16
    k_fc_splitk<<<dim3(4, 96), 256, 0, stream>>>(feat, enc0_w, partial, 3 * NN, FC0, 64);
    k_fc_reduce<<<(16 * FC0 + 255) / 256, 256, 0, stream>>>(partial, enc0_b, e0, FC0, 96, 1);
    k_fc_splitk<<<dim3(2, 64), 256, 0, stream>>>(e0, enc1_w, partial, FC0, FC1, 16);
    k_fc_reduce<<<(16 * FC1 + 255) / 256, 256, 0, stream>>>(partial, enc1_b, e1, FC1, 64, 1);
    k_fc_splitk<<<dim3(1, 32), 256, 0, stream>>>(e1, enc2_w, partial, FC1, OMIC, 16);
    k_fc_reduce<<<(16 * OMIC + 255) / 256, 256, 0, stream>>>(partial, enc2_b, e2, OMIC, 32, 1);
    k_last<<<1, 256, 0, stream>>>(e2, last_w, last_b, out);
}

// Round 3
// 533.007 us; speedup vs baseline: 2.2824x; 1.1798x over previous
//
#include <hip/hip_runtime.h>
#include <math.h>

#define NTN 32768
#define BB 16
#define NN 2048
#define IN_CH 128
#define HC 256
#define EREAL 524288
#define ETOT (EREAL + NTN)
#define FC0 1024
#define FC1 512
#define OMIC 128
#define OUTD 2

typedef __attribute__((ext_vector_type(8))) short bf16x8;
typedef __attribute__((ext_vector_type(4))) float f32x4;

static __device__ __forceinline__ float wave_sum(float v) {
    for (int o = 32; o; o >>= 1) v += __shfl_xor(v, o);
    return v;
}
static __device__ __forceinline__ unsigned short f2bf(float f) {
    unsigned u = __float_as_uint(f);
    unsigned r = (u + 0x7fff + ((u >> 16) & 1)) >> 16;
    return (unsigned short)r;
}
static __device__ __forceinline__ float bf2f(unsigned short h) {
    return __uint_as_float(((unsigned)h) << 16);
}

// ---- per-node mean over IN_CH (one wave per node) ----
__global__ __launch_bounds__(256) void k_mean(const float* __restrict__ x, float* __restrict__ xmean) {
    int wave = threadIdx.x >> 6, lane = threadIdx.x & 63;
    int n = blockIdx.x * 4 + wave;
    float2 v = *(const float2*)(x + (size_t)n * IN_CH + lane * 2);
    float s = wave_sum(v.x + v.y);
    if (lane == 0) xmean[n] = s * (1.0f / 128.0f);
}

// ---- casts ----
__global__ __launch_bounds__(256) void k_cast_x(const float* __restrict__ x, unsigned short* __restrict__ xb) {
    int i = blockIdx.x * 256 + threadIdx.x;
    float4 v = ((const float4*)x)[i];
    ushort4 o;
    o.x = f2bf(v.x); o.y = f2bf(v.y); o.z = f2bf(v.z); o.w = f2bf(v.w);
    ((ushort4*)xb)[i] = o;
}
// out[n*K+k] = bf16(w[k*N + n])  (N=HC)
__global__ __launch_bounds__(256) void k_cast_wt(const float* __restrict__ w, unsigned short* __restrict__ wt, int K) {
    int idx = blockIdx.x * 256 + threadIdx.x;
    int n = idx / K, k = idx % K;
    wt[idx] = f2bf(w[(size_t)k * HC + n]);
}

// ---- CSR build ----
__global__ void k_deg(const int* __restrict__ ei, int* __restrict__ deg) {
    int e = blockIdx.x * 256 + threadIdx.x;
    if (e < EREAL) atomicAdd(&deg[ei[EREAL + e]], 1);
}

__global__ __launch_bounds__(1024) void k_scan(const int* __restrict__ deg, int* __restrict__ rowptr,
                                               int* __restrict__ cursor) {
    __shared__ int sd[1024];
    int t = threadIdx.x;
    int base = t * 32;
    int loc[32];
    int s = 0;
    for (int j = 0; j < 32; j++) { int d = deg[base + j] + 1; loc[j] = d; s += d; }
    sd[t] = s; __syncthreads();
    for (int o = 1; o < 1024; o <<= 1) {
        int v = (t >= o) ? sd[t - o] : 0;
        __syncthreads();
        sd[t] += v;
        __syncthreads();
    }
    int run = sd[t] - s;  // exclusive prefix
    for (int j = 0; j < 32; j++) { rowptr[base + j] = run; cursor[base + j] = run; run += loc[j]; }
    if (t == 1023) rowptr[NTN] = run;
}

__global__ void k_fill(const int* __restrict__ ei, int* __restrict__ cursor, int* __restrict__ csr) {
    int e = blockIdx.x * 256 + threadIdx.x;
    if (e >= ETOT) return;
    int s, d;
    if (e < EREAL) { s = ei[e]; d = ei[EREAL + e]; } else { s = d = e - EREAL; }
    int pos = atomicAdd(&cursor[d], 1);
    csr[pos] = s;
}

// ---- bf16 MFMA GEMM: C[M,256] = A[M,K] @ Bt[256,K]^T, fused att head-dots ----
// grid (4, M/128), block 256 (4 waves). Tile M=128, N=64 (= one head), BK=64.
// Per wave: 32x64 via acc[2][4] of 16x16x32 MFMAs.
__global__ __launch_bounds__(256) void k_gemm_mfma(
    const unsigned short* __restrict__ A, const unsigned short* __restrict__ Bt, int K,
    const float* __restrict__ attS, const float* __restrict__ attD,
    unsigned short* __restrict__ Cout, float* __restrict__ aS, float* __restrict__ aD) {
    __shared__ unsigned short As[128][72];  // +8 pad: 144B stride -> 2-way bank alias (free)
    __shared__ unsigned short Bs[64][72];
    const int t = threadIdx.x;
    const int lane = t & 63, wave = t >> 6;
    const int quad = lane >> 4, l16 = lane & 15;
    const int bx = blockIdx.x, by = blockIdx.y;
    const int arow = t >> 1, acol = (t & 1) * 32;   // 128 rows x 64B
    const int brow = t >> 2, bcol = (t & 3) * 16;   // 64 rows x 32B
    const unsigned short* Ag = A + (size_t)(by * 128 + arow) * K + acol;
    const unsigned short* Bg = Bt + (size_t)(bx * 64 + brow) * K + bcol;
    f32x4 acc[2][4] = {};
    for (int k0 = 0; k0 < K; k0 += 64) {
        uint4 a0 = *(const uint4*)(Ag + k0);
        uint4 a1 = *(const uint4*)(Ag + k0 + 8);
        uint4 a2 = *(const uint4*)(Ag + k0 + 16);
        uint4 a3 = *(const uint4*)(Ag + k0 + 24);
        uint4 b0 = *(const uint4*)(Bg + k0);
        uint4 b1 = *(const uint4*)(Bg + k0 + 8);
        __syncthreads();
        *(uint4*)&As[arow][acol +  0] = a0;
        *(uint4*)&As[arow][acol +  8] = a1;
        *(uint4*)&As[arow][acol + 16] = a2;
        *(uint4*)&As[arow][acol + 24] = a3;
        *(uint4*)&Bs[brow][bcol +  0] = b0;
        *(uint4*)&Bs[brow][bcol +  8] = b1;
        __syncthreads();
#pragma unroll
        for (int kc = 0; kc < 64; kc += 32) {
            bf16x8 af[2], bfr[4];
#pragma unroll
            for (int mt = 0; mt < 2; mt++)
                af[mt] = *(const bf16x8*)&As[wave * 32 + mt * 16 + l16][kc + quad * 8];
#pragma unroll
            for (int nt = 0; nt < 4; nt++)
                bfr[nt] = *(const bf16x8*)&Bs[nt * 16 + l16][kc + quad * 8];
#pragma unroll
            for (int mt = 0; mt < 2; mt++)
#pragma unroll
                for (int nt = 0; nt < 4; nt++)
                    acc[mt][nt] = __builtin_amdgcn_mfma_f32_16x16x32_bf16(af[mt], bfr[nt], acc[mt][nt], 0, 0, 0);
        }
    }
    float as_l[4], ad_l[4];
#pragma unroll
    for (int nt = 0; nt < 4; nt++) {
        int gcol = bx * 64 + nt * 16 + l16;
        as_l[nt] = attS[gcol];
        ad_l[nt] = attD[gcol];
    }
#pragma unroll
    for (int mt = 0; mt < 2; mt++) {
#pragma unroll
        for (int reg = 0; reg < 4; reg++) {
            int grow = by * 128 + wave * 32 + mt * 16 + quad * 4 + reg;
            float ps = 0.f, pd = 0.f;
#pragma unroll
            for (int nt = 0; nt < 4; nt++) {
                float v = acc[mt][nt][reg];
                Cout[(size_t)grow * HC + bx * 64 + nt * 16 + l16] = f2bf(v);
                ps += v * as_l[nt];
                pd += v * ad_l[nt];
            }
            for (int o = 8; o; o >>= 1) { ps += __shfl_xor(ps, o); pd += __shfl_xor(pd, o); }
            if (l16 == 0) { aS[grow * 4 + bx] = ps; aD[grow * 4 + bx] = pd; }
        }
    }
}

// ---- attention softmax + aggregate + bias + ELU + pool (one wave per node, bf16 rows) ----
__global__ __launch_bounds__(256) void k_agg(
    const unsigned short* __restrict__ xw, const float* __restrict__ aS, const float* __restrict__ aD,
    const int* __restrict__ rowptr, const int* __restrict__ csr,
    const float* __restrict__ bias, const float* __restrict__ poolw, const float* __restrict__ poolb,
    unsigned short* __restrict__ hout, float* __restrict__ xpre) {
    int wave = threadIdx.x >> 6, lane = threadIdx.x & 63;
    int n = blockIdx.x * 4 + wave;
    int beg = rowptr[n], end = rowptr[n + 1];
    float4 ad4 = *(const float4*)(aD + n * 4);
    float m[4] = {-INFINITY, -INFINITY, -INFINITY, -INFINITY};
    for (int i = beg + lane; i < end; i += 64) {
        int s = csr[i];
        float4 as4 = *(const float4*)(aS + s * 4);
        float a0 = as4.x + ad4.x; a0 = a0 > 0.f ? a0 : 0.2f * a0; m[0] = fmaxf(m[0], a0);
        float a1 = as4.y + ad4.y; a1 = a1 > 0.f ? a1 : 0.2f * a1; m[1] = fmaxf(m[1], a1);
        float a2 = as4.z + ad4.z; a2 = a2 > 0.f ? a2 : 0.2f * a2; m[2] = fmaxf(m[2], a2);
        float a3 = as4.w + ad4.w; a3 = a3 > 0.f ? a3 : 0.2f * a3; m[3] = fmaxf(m[3], a3);
    }
#pragma unroll
    for (int h = 0; h < 4; h++)
        for (int o = 32; o; o >>= 1) m[h] = fmaxf(m[h], __shfl_xor(m[h], o));
    float l[4] = {0.f, 0.f, 0.f, 0.f};
    for (int i = beg + lane; i < end; i += 64) {
        int s = csr[i];
        float4 as4 = *(const float4*)(aS + s * 4);
        float a0 = as4.x + ad4.x; a0 = a0 > 0.f ? a0 : 0.2f * a0; l[0] += expf(a0 - m[0]);
        float a1 = as4.y + ad4.y; a1 = a1 > 0.f ? a1 : 0.2f * a1; l[1] += expf(a1 - m[1]);
        float a2 = as4.z + ad4.z; a2 = a2 > 0.f ? a2 : 0.2f * a2; l[2] += expf(a2 - m[2]);
        float a3 = as4.w + ad4.w; a3 = a3 > 0.f ? a3 : 0.2f * a3; l[3] += expf(a3 - m[3]);
    }
    float invl[4];
#pragma unroll
    for (int h = 0; h < 4; h++) { l[h] = wave_sum(l[h]); invl[h] = 1.0f / (l[h] + 1e-16f); }
    int hd = lane >> 4;
    float mh = m[hd], il = invl[hd];
    float adh = (hd == 0) ? ad4.x : (hd == 1) ? ad4.y : (hd == 2) ? ad4.z : ad4.w;
    float4 acc = {0.f, 0.f, 0.f, 0.f};
    for (int i = beg; i < end; i++) {
        int s = csr[i];
        float a = aS[s * 4 + hd] + adh;
        a = a > 0.f ? a : 0.2f * a;
        float coef = expf(a - mh) * il;
        ushort4 v = *(const ushort4*)(xw + (size_t)s * HC + lane * 4);
        acc.x += bf2f(v.x) * coef; acc.y += bf2f(v.y) * coef;
        acc.z += bf2f(v.z) * coef; acc.w += bf2f(v.w) * coef;
    }
    float4 bv = *(const float4*)(bias + lane * 4);
    float4 r;
    r.x = acc.x + bv.x; r.x = r.x > 0.f ? r.x : expm1f(r.x);
    r.y = acc.y + bv.y; r.y = r.y > 0.f ? r.y : expm1f(r.y);
    r.z = acc.z + bv.z; r.z = r.z > 0.f ? r.z : expm1f(r.z);
    r.w = acc.w + bv.w; r.w = r.w > 0.f ? r.w : expm1f(r.w);
    if (hout) {
        ushort4 o;
        o.x = f2bf(r.x); o.y = f2bf(r.y); o.z = f2bf(r.z); o.w = f2bf(r.w);
        *(ushort4*)(hout + (size_t)n * HC + lane * 4) = o;
    }
    float4 pw = *(const float4*)(poolw + lane * 4);
    float p = r.x * pw.x + r.y * pw.y + r.z * pw.z + r.w * pw.w;
    p = wave_sum(p);
    if (lane == 0) xpre[n] = p + poolb[0];
}

// ---- LayerNorm over rows of [B, NN]; dst already offset to the feat column block ----
__global__ __launch_bounds__(256) void k_ln(const float* __restrict__ src, const float* __restrict__ lw,
                                            const float* __restrict__ lb, float* __restrict__ dst) {
    __shared__ float r0[256], r1[256];
    int row = blockIdx.x, t = threadIdx.x;
    float v[8];
    float s = 0.f, s2 = 0.f;
#pragma unroll
    for (int j = 0; j < 8; j++) {
        float x = src[(size_t)row * NN + t + j * 256];
        v[j] = x; s += x; s2 += x * x;
    }
    r0[t] = s; r1[t] = s2; __syncthreads();
    for (int o = 128; o; o >>= 1) {
        if (t < o) { r0[t] += r0[t + o]; r1[t] += r1[t + o]; }
        __syncthreads();
    }
    float mu = r0[0] * (1.0f / NN);
    float var = r1[0] * (1.0f / NN) - mu * mu;
    float rs = rsqrtf(var + 1e-5f);
#pragma unroll
    for (int j = 0; j < 8; j++) {
        int idx = t + j * 256;
        dst[(size_t)row * (3 * NN) + idx] = (v[j] - mu) * rs * lw[idx] + lb[idx];
    }
}

// ---- split-K FC stage 1 ----
__global__ __launch_bounds__(256) void k_fc_splitk(const float* __restrict__ In, const float* __restrict__ W,
                                                   float* __restrict__ partial, int K, int Nc, int KC) {
    int col = blockIdx.x * 256 + threadIdx.x;
    int k0 = blockIdx.y * KC;
    float acc[16] = {};
    if (col < Nc) {
        const float* wp = W + (size_t)k0 * Nc + col;
#pragma unroll 4
        for (int kk = 0; kk < KC; kk++) {
            float w = wp[(size_t)kk * Nc];
#pragma unroll
            for (int r = 0; r < 16; r++) acc[r] += In[r * K + k0 + kk] * w;
        }
        float* pp = partial + ((size_t)blockIdx.y * 16) * Nc + col;
#pragma unroll
        for (int r = 0; r < 16; r++) pp[(size_t)r * Nc] = acc[r];
    }
}

// ---- split-K FC stage 2 ----
__global__ __launch_bounds__(256) void k_fc_reduce(const float* __restrict__ partial, const float* __restrict__ bias,
                                                   float* __restrict__ Out, int Nc, int KS, int doElu) {
    int idx = blockIdx.x * 256 + threadIdx.x;
    if (idx >= 16 * Nc) return;
    int col = idx % Nc;
    float s = bias[col];
    for (int ks = 0; ks < KS; ks++) s += partial[(size_t)ks * 16 * Nc + idx];
    if (doElu) s = s > 0.f ? s : expm1f(s);
    Out[idx] = s;
}

// ---- last layer ----
__global__ __launch_bounds__(256) void k_last(const float* __restrict__ In, const float* __restrict__ W,
                                              const float* __restrict__ b, float* __restrict__ Out) {
    int t = threadIdx.x;
    int r = t >> 4, c = (t >> 3) & 1, ksub = t & 7;
    float s = 0.f;
    for (int k = ksub; k < OMIC; k += 8) s += In[r * OMIC + k] * W[k * OUTD + c];
    for (int o = 1; o < 8; o <<= 1) s += __shfl_xor(s, o);
    if (ksub == 0) Out[r * OUTD + c] = s + b[c];
}

extern "C" void kernel_launch(void* const* d_in, const int* in_sizes, int n_in,
                              void* d_out, int out_size, void* d_ws, size_t ws_size,
                              hipStream_t stream) {
    (void)in_sizes; (void)n_in; (void)out_size; (void)ws_size;
    const float* x        = (const float*)d_in[0];
    const int*   ei       = (const int*)d_in[1];
    const float* w1       = (const float*)d_in[2];
    const float* att_src1 = (const float*)d_in[3];
    const float* att_dst1 = (const float*)d_in[4];
    const float* bias1    = (const float*)d_in[5];
    const float* pool1_w  = (const float*)d_in[6];
    const float* pool1_b  = (const float*)d_in[7];
    const float* w2       = (const float*)d_in[8];
    const float* att_src2 = (const float*)d_in[9];
    const float* att_dst2 = (const float*)d_in[10];
    const float* bias2    = (const float*)d_in[11];
    const float* pool2_w  = (const float*)d_in[12];
    const float* pool2_b  = (const float*)d_in[13];
    const float* ln_w     = (const float*)d_in[14];
    const float* ln_b     = (const float*)d_in[15];
    const float* enc0_w   = (const float*)d_in[16];
    const float* enc0_b   = (const float*)d_in[17];
    const float* enc1_w   = (const float*)d_in[18];
    const float* enc1_b   = (const float*)d_in[19];
    const float* enc2_w   = (const float*)d_in[20];
    const float* enc2_b   = (const float*)d_in[21];
    const float* last_w   = (const float*)d_in[22];
    const float* last_b   = (const float*)d_in[23];
    float* out = (float*)d_out;

    char* p = (char*)d_ws;
    auto alloc = [&](size_t bytes) -> void* {
        void* r = (void*)p;
        p += (bytes + 255) & ~(size_t)255;
        return r;
    };
    unsigned short* xwb  = (unsigned short*)alloc((size_t)NTN * HC * 2);   // bf16 messages
    unsigned short* hb   = (unsigned short*)alloc((size_t)NTN * HC * 2);   // bf16 layer-2 input
    unsigned short* xb   = (unsigned short*)alloc((size_t)NTN * IN_CH * 2);
    unsigned short* w1t  = (unsigned short*)alloc((size_t)HC * IN_CH * 2);
    unsigned short* w2t  = (unsigned short*)alloc((size_t)HC * HC * 2);
    float* a_src  = (float*)alloc((size_t)NTN * 4 * 4);
    float* a_dst  = (float*)alloc((size_t)NTN * 4 * 4);
    float* xmean  = (float*)alloc((size_t)NTN * 4);
    float* x1pre  = (float*)alloc((size_t)NTN * 4);
    float* x2pre  = (float*)alloc((size_t)NTN * 4);
    float* feat   = (float*)alloc((size_t)BB * 3 * NN * 4);
    float* e0     = (float*)alloc((size_t)BB * FC0 * 4);
    float* e1     = (float*)alloc((size_t)BB * FC1 * 4);
    float* e2     = (float*)alloc((size_t)BB * OMIC * 4);
    float* partial= (float*)alloc((size_t)96 * 16 * FC0 * 4);
    int*   deg    = (int*)alloc((size_t)NTN * 4);
    int*   rowptr = (int*)alloc((size_t)(NTN + 1) * 4);
    int*   cursor = (int*)alloc((size_t)NTN * 4);
    int*   csr    = (int*)alloc((size_t)ETOT * 4);

    hipMemsetAsync(deg, 0, (size_t)NTN * 4, stream);

    k_cast_x<<<(NTN * IN_CH / 4 + 255) / 256, 256, 0, stream>>>(x, xb);
    k_cast_wt<<<(HC * IN_CH + 255) / 256, 256, 0, stream>>>(w1, w1t, IN_CH);
    k_cast_wt<<<(HC * HC + 255) / 256, 256, 0, stream>>>(w2, w2t, HC);
    k_mean<<<NTN / 4, 256, 0, stream>>>(x, xmean);
    k_deg<<<(EREAL + 255) / 256, 256, 0, stream>>>(ei, deg);
    k_scan<<<1, 1024, 0, stream>>>(deg, rowptr, cursor);
    k_fill<<<(ETOT + 255) / 256, 256, 0, stream>>>(ei, cursor, csr);

    // GAT layer 1
    k_gemm_mfma<<<dim3(4, NTN / 128), 256, 0, stream>>>(xb, w1t, IN_CH, att_src1, att_dst1, xwb, a_src, a_dst);
    k_ln<<<BB, 256, 0, stream>>>(xmean, ln_w, ln_b, feat + 0);
    k_agg<<<NTN / 4, 256, 0, stream>>>(xwb, a_src, a_dst, rowptr, csr, bias1, pool1_w, pool1_b, hb, x1pre);
    k_ln<<<BB, 256, 0, stream>>>(x1pre, ln_w, ln_b, feat + NN);

    // GAT layer 2
    k_gemm_mfma<<<dim3(4, NTN / 128), 256, 0, stream>>>(hb, w2t, HC, att_src2, att_dst2, xwb, a_src, a_dst);
    k_agg<<<NTN / 4, 256, 0, stream>>>(xwb, a_src, a_dst, rowptr, csr, bias2, pool2_w, pool2_b, (unsigned short*)nullptr, x2pre);
    k_ln<<<BB, 256, 0, stream>>>(x2pre, ln_w, ln_b, feat + 2 * NN);

    // encoder MLP (split-K)
    k_fc_splitk<<<dim3(4, 96), 256, 0, stream>>>(feat, enc0_w, partial, 3 * NN, FC0, 64);
    k_fc_reduce<<<(16 * FC0 + 255) / 256, 256, 0, stream>>>(partial, enc0_b, e0, FC0, 96, 1);
    k_fc_splitk<<<dim3(2, 64), 256, 0, stream>>>(e0, enc1_w, partial, FC0, FC1, 16);
    k_fc_reduce<<<(16 * FC1 + 255) / 256, 256, 0, stream>>>(partial, enc1_b, e1, FC1, 64, 1);
    k_fc_splitk<<<dim3(1, 32), 256, 0, stream>>>(e1, enc2_w, partial, FC1, OMIC, 16);
    k_fc_reduce<<<(16 * OMIC + 255) / 256, 256, 0, stream>>>(partial, enc2_b, e2, OMIC, 32, 1);
    k_last<<<1, 256, 0, stream>>>(e2, last_w, last_b, out);
}

// Round 4
// 472.824 us; speedup vs baseline: 2.5729x; 1.1273x over previous
//
#include <hip/hip_runtime.h>
#include <math.h>

#define NTN 32768
#define BB 16
#define NN 2048
#define IN_CH 128
#define HC 256
#define EREAL 524288
#define ETOT (EREAL + NTN)
#define FC0 1024
#define FC1 512
#define OMIC 128
#define OUTD 2
#define CAP 96

typedef __attribute__((ext_vector_type(8))) short bf16x8;
typedef __attribute__((ext_vector_type(4))) float f32x4;

static __device__ __forceinline__ float wave_sum(float v) {
    for (int o = 32; o; o >>= 1) v += __shfl_xor(v, o);
    return v;
}
static __device__ __forceinline__ unsigned short f2bf(float f) {
    unsigned u = __float_as_uint(f);
    unsigned r = (u + 0x7fff + ((u >> 16) & 1)) >> 16;
    return (unsigned short)r;
}
static __device__ __forceinline__ float bf2f(unsigned short h) {
    return __uint_as_float(((unsigned)h) << 16);
}

// ---- fused cast x->bf16 + per-node mean (one wave per node) ----
__global__ __launch_bounds__(256) void k_prep(const float* __restrict__ x, unsigned short* __restrict__ xb,
                                              float* __restrict__ xmean) {
    int wave = threadIdx.x >> 6, lane = threadIdx.x & 63;
    int n = blockIdx.x * 4 + wave;
    float2 v = *(const float2*)(x + (size_t)n * IN_CH + lane * 2);
    ushort2 o;
    o.x = f2bf(v.x); o.y = f2bf(v.y);
    *(ushort2*)(xb + (size_t)n * IN_CH + lane * 2) = o;
    float s = wave_sum(v.x + v.y);
    if (lane == 0) xmean[n] = s * (1.0f / 128.0f);
}

// ---- both weight transpose-casts in one launch ----
__global__ __launch_bounds__(256) void k_castw(const float* __restrict__ w1, const float* __restrict__ w2,
                                               unsigned short* __restrict__ w1t, unsigned short* __restrict__ w2t) {
    int idx = blockIdx.x * 256 + threadIdx.x;
    if (idx < HC * IN_CH) {
        int n = idx / IN_CH, k = idx % IN_CH;
        w1t[idx] = f2bf(w1[(size_t)k * HC + n]);
    } else {
        int j = idx - HC * IN_CH;
        int n = j / HC, k = j % HC;
        w2t[j] = f2bf(w2[(size_t)k * HC + n]);
    }
}

// ---- CSR build ----
__global__ void k_deg(const int* __restrict__ ei, int* __restrict__ deg) {
    int e = blockIdx.x * 256 + threadIdx.x;
    if (e < EREAL) atomicAdd(&deg[ei[EREAL + e]], 1);
}

__global__ __launch_bounds__(1024) void k_scan(const int* __restrict__ deg, int* __restrict__ rowptr,
                                               int* __restrict__ cursor) {
    __shared__ int sd[1024];
    int t = threadIdx.x;
    int base = t * 32;
    int loc[32];
    int s = 0;
    for (int j = 0; j < 32; j++) { int d = deg[base + j] + 1; loc[j] = d; s += d; }
    sd[t] = s; __syncthreads();
    for (int o = 1; o < 1024; o <<= 1) {
        int v = (t >= o) ? sd[t - o] : 0;
        __syncthreads();
        sd[t] += v;
        __syncthreads();
    }
    int run = sd[t] - s;  // exclusive prefix
    for (int j = 0; j < 32; j++) { rowptr[base + j] = run; cursor[base + j] = run; run += loc[j]; }
    if (t == 1023) rowptr[NTN] = run;
}

__global__ void k_fill(const int* __restrict__ ei, int* __restrict__ cursor, int* __restrict__ csr) {
    int e = blockIdx.x * 256 + threadIdx.x;
    if (e >= ETOT) return;
    int s, d;
    if (e < EREAL) { s = ei[e]; d = ei[EREAL + e]; } else { s = d = e - EREAL; }
    int pos = atomicAdd(&cursor[d], 1);
    csr[pos] = s;
}

// ---- bf16 MFMA GEMM: C[M,256] = A[M,K] @ Bt[256,K]^T, fused att head-dots ----
__global__ __launch_bounds__(256) void k_gemm_mfma(
    const unsigned short* __restrict__ A, const unsigned short* __restrict__ Bt, int K,
    const float* __restrict__ attS, const float* __restrict__ attD,
    unsigned short* __restrict__ Cout, float* __restrict__ aS, float* __restrict__ aD) {
    __shared__ unsigned short As[128][72];
    __shared__ unsigned short Bs[64][72];
    const int t = threadIdx.x;
    const int lane = t & 63, wave = t >> 6;
    const int quad = lane >> 4, l16 = lane & 15;
    const int bx = blockIdx.x, by = blockIdx.y;
    const int arow = t >> 1, acol = (t & 1) * 32;
    const int brow = t >> 2, bcol = (t & 3) * 16;
    const unsigned short* Ag = A + (size_t)(by * 128 + arow) * K + acol;
    const unsigned short* Bg = Bt + (size_t)(bx * 64 + brow) * K + bcol;
    f32x4 acc[2][4] = {};
    for (int k0 = 0; k0 < K; k0 += 64) {
        uint4 a0 = *(const uint4*)(Ag + k0);
        uint4 a1 = *(const uint4*)(Ag + k0 + 8);
        uint4 a2 = *(const uint4*)(Ag + k0 + 16);
        uint4 a3 = *(const uint4*)(Ag + k0 + 24);
        uint4 b0 = *(const uint4*)(Bg + k0);
        uint4 b1 = *(const uint4*)(Bg + k0 + 8);
        __syncthreads();
        *(uint4*)&As[arow][acol +  0] = a0;
        *(uint4*)&As[arow][acol +  8] = a1;
        *(uint4*)&As[arow][acol + 16] = a2;
        *(uint4*)&As[arow][acol + 24] = a3;
        *(uint4*)&Bs[brow][bcol +  0] = b0;
        *(uint4*)&Bs[brow][bcol +  8] = b1;
        __syncthreads();
#pragma unroll
        for (int kc = 0; kc < 64; kc += 32) {
            bf16x8 af[2], bfr[4];
#pragma unroll
            for (int mt = 0; mt < 2; mt++)
                af[mt] = *(const bf16x8*)&As[wave * 32 + mt * 16 + l16][kc + quad * 8];
#pragma unroll
            for (int nt = 0; nt < 4; nt++)
                bfr[nt] = *(const bf16x8*)&Bs[nt * 16 + l16][kc + quad * 8];
#pragma unroll
            for (int mt = 0; mt < 2; mt++)
#pragma unroll
                for (int nt = 0; nt < 4; nt++)
                    acc[mt][nt] = __builtin_amdgcn_mfma_f32_16x16x32_bf16(af[mt], bfr[nt], acc[mt][nt], 0, 0, 0);
        }
    }
    float as_l[4], ad_l[4];
#pragma unroll
    for (int nt = 0; nt < 4; nt++) {
        int gcol = bx * 64 + nt * 16 + l16;
        as_l[nt] = attS[gcol];
        ad_l[nt] = attD[gcol];
    }
#pragma unroll
    for (int mt = 0; mt < 2; mt++) {
#pragma unroll
        for (int reg = 0; reg < 4; reg++) {
            int grow = by * 128 + wave * 32 + mt * 16 + quad * 4 + reg;
            float ps = 0.f, pd = 0.f;
#pragma unroll
            for (int nt = 0; nt < 4; nt++) {
                float v = acc[mt][nt][reg];
                Cout[(size_t)grow * HC + bx * 64 + nt * 16 + l16] = f2bf(v);
                ps += v * as_l[nt];
                pd += v * ad_l[nt];
            }
            for (int o = 8; o; o >>= 1) { ps += __shfl_xor(ps, o); pd += __shfl_xor(pd, o); }
            if (l16 == 0) { aS[grow * 4 + bx] = ps; aD[grow * 4 + bx] = pd; }
        }
    }
}

// ---- attention aggregate: 2 nodes/block, 2 waves/node (edge-split), ea cached in LDS ----
__global__ __launch_bounds__(256) void k_agg(
    const unsigned short* __restrict__ xw, const float* __restrict__ aS, const float* __restrict__ aD,
    const int* __restrict__ rowptr, const int* __restrict__ csr,
    const float* __restrict__ bias, const float* __restrict__ poolw, const float* __restrict__ poolb,
    unsigned short* __restrict__ hout, float* __restrict__ xpre) {
    __shared__ float ea_s[2][CAP][4];    // [node][slot][head]
    __shared__ float part[2][2][256];    // [node][half][channel]
    __shared__ float lpart[2][2][4];
    int t = threadIdx.x;
    int wave = t >> 6, lane = t & 63;
    int nd = wave >> 1, half = wave & 1;
    int n = blockIdx.x * 2 + nd;
    int beg = rowptr[n], end = rowptr[n + 1];
    int deg = end - beg;
    int mid = beg + ((deg + 1) >> 1);
    int wbeg = half ? mid : beg;
    int wend = half ? end : mid;
    float4 ad4 = *(const float4*)(aD + n * 4);
    // phase L: exp(alpha) for my half (no max subtraction: |alpha| << 1, no overflow)
    float l0 = 0.f, l1 = 0.f, l2 = 0.f, l3 = 0.f;
    for (int i = wbeg + lane; i < wend; i += 64) {
        int s = csr[i];
        float4 as4 = *(const float4*)(aS + s * 4);
        float a0 = as4.x + ad4.x; a0 = a0 > 0.f ? a0 : 0.2f * a0; float e0 = __expf(a0);
        float a1 = as4.y + ad4.y; a1 = a1 > 0.f ? a1 : 0.2f * a1; float e1 = __expf(a1);
        float a2 = as4.z + ad4.z; a2 = a2 > 0.f ? a2 : 0.2f * a2; float e2 = __expf(a2);
        float a3 = as4.w + ad4.w; a3 = a3 > 0.f ? a3 : 0.2f * a3; float e3 = __expf(a3);
        l0 += e0; l1 += e1; l2 += e2; l3 += e3;
        int j = i - beg;
        if (j < CAP) {
            float4 e4; e4.x = e0; e4.y = e1; e4.z = e2; e4.w = e3;
            *(float4*)&ea_s[nd][j][0] = e4;
        }
    }
    l0 = wave_sum(l0); l1 = wave_sum(l1); l2 = wave_sum(l2); l3 = wave_sum(l3);
    if (lane == 0) {
        lpart[nd][half][0] = l0; lpart[nd][half][1] = l1;
        lpart[nd][half][2] = l2; lpart[nd][half][3] = l3;
    }
    __syncthreads();
    int hd = lane >> 4;
    float ilh = 1.0f / (lpart[nd][0][hd] + lpart[nd][1][hd] + 1e-16f);
    float adh = (hd == 0) ? ad4.x : (hd == 1) ? ad4.y : (hd == 2) ? ad4.z : ad4.w;
    float4 acc = {0.f, 0.f, 0.f, 0.f};
    float4 accB = {0.f, 0.f, 0.f, 0.f};
    if (deg <= CAP) {
        int i = wbeg;
        for (; i + 2 <= wend; i += 2) {
            int s0 = csr[i], s1 = csr[i + 1];
            float e0 = ea_s[nd][i - beg][hd];
            float e1 = ea_s[nd][i - beg + 1][hd];
            ushort4 v0 = *(const ushort4*)(xw + (size_t)s0 * HC + lane * 4);
            ushort4 v1 = *(const ushort4*)(xw + (size_t)s1 * HC + lane * 4);
            acc.x += bf2f(v0.x) * e0;  acc.y += bf2f(v0.y) * e0;
            acc.z += bf2f(v0.z) * e0;  acc.w += bf2f(v0.w) * e0;
            accB.x += bf2f(v1.x) * e1; accB.y += bf2f(v1.y) * e1;
            accB.z += bf2f(v1.z) * e1; accB.w += bf2f(v1.w) * e1;
        }
        if (i < wend) {
            int s0 = csr[i];
            float e0 = ea_s[nd][i - beg][hd];
            ushort4 v0 = *(const ushort4*)(xw + (size_t)s0 * HC + lane * 4);
            acc.x += bf2f(v0.x) * e0; acc.y += bf2f(v0.y) * e0;
            acc.z += bf2f(v0.z) * e0; acc.w += bf2f(v0.w) * e0;
        }
    } else {
        // overflow fallback (statistically never for this graph)
        for (int i = wbeg; i < wend; i++) {
            int s = csr[i];
            float a = aS[s * 4 + hd] + adh;
            a = a > 0.f ? a : 0.2f * a;
            float e = __expf(a);
            ushort4 v = *(const ushort4*)(xw + (size_t)s * HC + lane * 4);
            acc.x += bf2f(v.x) * e; acc.y += bf2f(v.y) * e;
            acc.z += bf2f(v.z) * e; acc.w += bf2f(v.w) * e;
        }
    }
    acc.x += accB.x; acc.y += accB.y; acc.z += accB.z; acc.w += accB.w;
    *(float4*)&part[nd][half][lane * 4] = acc;
    __syncthreads();
    if (half == 0) {
        float4 p0 = *(const float4*)&part[nd][0][lane * 4];
        float4 p1 = *(const float4*)&part[nd][1][lane * 4];
        float4 bv = *(const float4*)(bias + lane * 4);
        float4 r;
        r.x = (p0.x + p1.x) * ilh + bv.x; r.x = r.x > 0.f ? r.x : expm1f(r.x);
        r.y = (p0.y + p1.y) * ilh + bv.y; r.y = r.y > 0.f ? r.y : expm1f(r.y);
        r.z = (p0.z + p1.z) * ilh + bv.z; r.z = r.z > 0.f ? r.z : expm1f(r.z);
        r.w = (p0.w + p1.w) * ilh + bv.w; r.w = r.w > 0.f ? r.w : expm1f(r.w);
        if (hout) {
            ushort4 o;
            o.x = f2bf(r.x); o.y = f2bf(r.y); o.z = f2bf(r.z); o.w = f2bf(r.w);
            *(ushort4*)(hout + (size_t)n * HC + lane * 4) = o;
        }
        float4 pw = *(const float4*)(poolw + lane * 4);
        float p = r.x * pw.x + r.y * pw.y + r.z * pw.z + r.w * pw.w;
        p = wave_sum(p);
        if (lane == 0) xpre[n] = p + poolb[0];
    }
}

// ---- LayerNorm over rows of [B, NN]; dst offset to feat column block ----
__global__ __launch_bounds__(256) void k_ln(const float* __restrict__ src, const float* __restrict__ lw,
                                            const float* __restrict__ lb, float* __restrict__ dst) {
    __shared__ float r0[256], r1[256];
    int row = blockIdx.x, t = threadIdx.x;
    float v[8];
    float s = 0.f, s2 = 0.f;
#pragma unroll
    for (int j = 0; j < 8; j++) {
        float x = src[(size_t)row * NN + t + j * 256];
        v[j] = x; s += x; s2 += x * x;
    }
    r0[t] = s; r1[t] = s2; __syncthreads();
    for (int o = 128; o; o >>= 1) {
        if (t < o) { r0[t] += r0[t + o]; r1[t] += r1[t + o]; }
        __syncthreads();
    }
    float mu = r0[0] * (1.0f / NN);
    float var = r1[0] * (1.0f / NN) - mu * mu;
    float rs = rsqrtf(var + 1e-5f);
#pragma unroll
    for (int j = 0; j < 8; j++) {
        int idx = t + j * 256;
        dst[(size_t)row * (3 * NN) + idx] = (v[j] - mu) * rs * lw[idx] + lb[idx];
    }
}

// ---- split-K FC stage 1 ----
__global__ __launch_bounds__(256) void k_fc_splitk(const float* __restrict__ In, const float* __restrict__ W,
                                                   float* __restrict__ partial, int K, int Nc, int KC) {
    int col = blockIdx.x * 256 + threadIdx.x;
    int k0 = blockIdx.y * KC;
    float acc[16] = {};
    if (col < Nc) {
        const float* wp = W + (size_t)k0 * Nc + col;
#pragma unroll 4
        for (int kk = 0; kk < KC; kk++) {
            float w = wp[(size_t)kk * Nc];
#pragma unroll
            for (int r = 0; r < 16; r++) acc[r] += In[r * K + k0 + kk] * w;
        }
        float* pp = partial + ((size_t)blockIdx.y * 16) * Nc + col;
#pragma unroll
        for (int r = 0; r < 16; r++) pp[(size_t)r * Nc] = acc[r];
    }
}

// ---- split-K FC stage 2 ----
__global__ __launch_bounds__(256) void k_fc_reduce(const float* __restrict__ partial, const float* __restrict__ bias,
                                                   float* __restrict__ Out, int Nc, int KS, int doElu) {
    int idx = blockIdx.x * 256 + threadIdx.x;
    if (idx >= 16 * Nc) return;
    int col = idx % Nc;
    float s = bias[col];
    for (int ks = 0; ks < KS; ks++) s += partial[(size_t)ks * 16 * Nc + idx];
    if (doElu) s = s > 0.f ? s : expm1f(s);
    Out[idx] = s;
}

// ---- fused tail: e2 = elu(e1 @ enc2_w + b), out = e2 @ last_w + last_b ----
__global__ __launch_bounds__(256) void k_tail(const float* __restrict__ e1, const float* __restrict__ w2,
                                              const float* __restrict__ b2, const float* __restrict__ lastw,
                                              const float* __restrict__ lastb, float* __restrict__ out) {
    __shared__ float in_s[16 * FC1];   // 32 KB
    __shared__ float e2_s[16 * OMIC];  // 8 KB
    int t = threadIdx.x;
    for (int i = t; i < 16 * FC1; i += 256) in_s[i] = e1[i];
    __syncthreads();
    int c = t & 127, rg = t >> 7;
    float acc[8] = {};
    for (int k = 0; k < FC1; k++) {
        float w = w2[(size_t)k * OMIC + c];
#pragma unroll
        for (int r = 0; r < 8; r++) acc[r] += in_s[(rg * 8 + r) * FC1 + k] * w;
    }
    float bb = b2[c];
#pragma unroll
    for (int r = 0; r < 8; r++) {
        float o = acc[r] + bb;
        o = o > 0.f ? o : expm1f(o);
        e2_s[(rg * 8 + r) * OMIC + c] = o;
    }
    __syncthreads();
    if (t < 32) {
        int r = t >> 1, cc = t & 1;
        float s = lastb[cc];
        for (int k = 0; k < OMIC; k++) s += e2_s[r * OMIC + k] * lastw[k * OUTD + cc];
        out[r * OUTD + cc] = s;
    }
}

extern "C" void kernel_launch(void* const* d_in, const int* in_sizes, int n_in,
                              void* d_out, int out_size, void* d_ws, size_t ws_size,
                              hipStream_t stream) {
    (void)in_sizes; (void)n_in; (void)out_size; (void)ws_size;
    const float* x        = (const float*)d_in[0];
    const int*   ei       = (const int*)d_in[1];
    const float* w1       = (const float*)d_in[2];
    const float* att_src1 = (const float*)d_in[3];
    const float* att_dst1 = (const float*)d_in[4];
    const float* bias1    = (const float*)d_in[5];
    const float* pool1_w  = (const float*)d_in[6];
    const float* pool1_b  = (const float*)d_in[7];
    const float* w2       = (const float*)d_in[8];
    const float* att_src2 = (const float*)d_in[9];
    const float* att_dst2 = (const float*)d_in[10];
    const float* bias2    = (const float*)d_in[11];
    const float* pool2_w  = (const float*)d_in[12];
    const float* pool2_b  = (const float*)d_in[13];
    const float* ln_w     = (const float*)d_in[14];
    const float* ln_b     = (const float*)d_in[15];
    const float* enc0_w   = (const float*)d_in[16];
    const float* enc0_b   = (const float*)d_in[17];
    const float* enc1_w   = (const float*)d_in[18];
    const float* enc1_b   = (const float*)d_in[19];
    const float* enc2_w   = (const float*)d_in[20];
    const float* enc2_b   = (const float*)d_in[21];
    const float* last_w   = (const float*)d_in[22];
    const float* last_b   = (const float*)d_in[23];
    float* out = (float*)d_out;

    char* p = (char*)d_ws;
    auto alloc = [&](size_t bytes) -> void* {
        void* r = (void*)p;
        p += (bytes + 255) & ~(size_t)255;
        return r;
    };
    unsigned short* xwb  = (unsigned short*)alloc((size_t)NTN * HC * 2);
    unsigned short* hb   = (unsigned short*)alloc((size_t)NTN * HC * 2);
    unsigned short* xb   = (unsigned short*)alloc((size_t)NTN * IN_CH * 2);
    unsigned short* w1t  = (unsigned short*)alloc((size_t)HC * IN_CH * 2);
    unsigned short* w2t  = (unsigned short*)alloc((size_t)HC * HC * 2);
    float* a_src  = (float*)alloc((size_t)NTN * 4 * 4);
    float* a_dst  = (float*)alloc((size_t)NTN * 4 * 4);
    float* xmean  = (float*)alloc((size_t)NTN * 4);
    float* x1pre  = (float*)alloc((size_t)NTN * 4);
    float* x2pre  = (float*)alloc((size_t)NTN * 4);
    float* feat   = (float*)alloc((size_t)BB * 3 * NN * 4);
    float* e0     = (float*)alloc((size_t)BB * FC0 * 4);
    float* e1     = (float*)alloc((size_t)BB * FC1 * 4);
    float* partial= (float*)alloc((size_t)96 * 16 * FC0 * 4);
    int*   deg    = (int*)alloc((size_t)NTN * 4);
    int*   rowptr = (int*)alloc((size_t)(NTN + 1) * 4);
    int*   cursor = (int*)alloc((size_t)NTN * 4);
    int*   csr    = (int*)alloc((size_t)ETOT * 4);

    hipMemsetAsync(deg, 0, (size_t)NTN * 4, stream);

    k_prep<<<NTN / 4, 256, 0, stream>>>(x, xb, xmean);
    k_castw<<<(HC * IN_CH + HC * HC) / 256, 256, 0, stream>>>(w1, w2, w1t, w2t);
    k_deg<<<(EREAL + 255) / 256, 256, 0, stream>>>(ei, deg);
    k_scan<<<1, 1024, 0, stream>>>(deg, rowptr, cursor);
    k_fill<<<(ETOT + 255) / 256, 256, 0, stream>>>(ei, cursor, csr);

    // GAT layer 1
    k_gemm_mfma<<<dim3(4, NTN / 128), 256, 0, stream>>>(xb, w1t, IN_CH, att_src1, att_dst1, xwb, a_src, a_dst);
    k_ln<<<BB, 256, 0, stream>>>(xmean, ln_w, ln_b, feat + 0);
    k_agg<<<NTN / 2, 256, 0, stream>>>(xwb, a_src, a_dst, rowptr, csr, bias1, pool1_w, pool1_b, hb, x1pre);
    k_ln<<<BB, 256, 0, stream>>>(x1pre, ln_w, ln_b, feat + NN);

    // GAT layer 2
    k_gemm_mfma<<<dim3(4, NTN / 128), 256, 0, stream>>>(hb, w2t, HC, att_src2, att_dst2, xwb, a_src, a_dst);
    k_agg<<<NTN / 2, 256, 0, stream>>>(xwb, a_src, a_dst, rowptr, csr, bias2, pool2_w, pool2_b, (unsigned short*)nullptr, x2pre);
    k_ln<<<BB, 256, 0, stream>>>(x2pre, ln_w, ln_b, feat + 2 * NN);

    // encoder MLP
    k_fc_splitk<<<dim3(4, 96), 256, 0, stream>>>(feat, enc0_w, partial, 3 * NN, FC0, 64);
    k_fc_reduce<<<(16 * FC0 + 255) / 256, 256, 0, stream>>>(partial, enc0_b, e0, FC0, 96, 1);
    k_fc_splitk<<<dim3(2, 64), 256, 0, stream>>>(e0, enc1_w, partial, FC0, FC1, 16);
    k_fc_reduce<<<(16 * FC1 + 255) / 256, 256, 0, stream>>>(partial, enc1_b, e1, FC1, 64, 1);
    k_tail<<<1, 256, 0, stream>>>(e1, enc2_w, enc2_b, last_w, last_b, out);
}

// Round 5
// 436.994 us; speedup vs baseline: 2.7839x; 1.0820x over previous
//
#include <hip/hip_runtime.h>
#include <math.h>

#define NTN 32768
#define BB 16
#define NN 2048
#define IN_CH 128
#define HC 256
#define EREAL 524288
#define ETOT (EREAL + NTN)
#define FC0 1024
#define FC1 512
#define OMIC 128
#define OUTD 2
#define CAP 96

#define PREP_BLKS (NTN / 4)
#define DEG_BLKS (EREAL / 256)
#define CASTW_BLKS ((HC * IN_CH + HC * HC) / 256)

typedef __attribute__((ext_vector_type(8))) short bf16x8;
typedef __attribute__((ext_vector_type(4))) float f32x4;

static __device__ __forceinline__ float wave_sum(float v) {
    for (int o = 32; o; o >>= 1) v += __shfl_xor(v, o);
    return v;
}
static __device__ __forceinline__ unsigned short f2bf(float f) {
    unsigned u = __float_as_uint(f);
    unsigned r = (u + 0x7fff + ((u >> 16) & 1)) >> 16;
    return (unsigned short)r;
}
static __device__ __forceinline__ float bf2f(unsigned short h) {
    return __uint_as_float(((unsigned)h) << 16);
}

// ---- fused: x->bf16 + mean | deg count + edge slot | weight transpose-casts ----
__global__ __launch_bounds__(256) void k_pre(
    const float* __restrict__ x, unsigned short* __restrict__ xb, float* __restrict__ xmean,
    const int* __restrict__ ei, int* __restrict__ deg, int* __restrict__ epos,
    const float* __restrict__ w1, const float* __restrict__ w2,
    unsigned short* __restrict__ w1t, unsigned short* __restrict__ w2t) {
    int b = blockIdx.x, t = threadIdx.x;
    if (b < PREP_BLKS) {
        int wave = t >> 6, lane = t & 63;
        int n = b * 4 + wave;
        float2 v = *(const float2*)(x + (size_t)n * IN_CH + lane * 2);
        ushort2 o;
        o.x = f2bf(v.x); o.y = f2bf(v.y);
        *(ushort2*)(xb + (size_t)n * IN_CH + lane * 2) = o;
        float s = wave_sum(v.x + v.y);
        if (lane == 0) xmean[n] = s * (1.0f / 128.0f);
    } else if (b < PREP_BLKS + DEG_BLKS) {
        int e = (b - PREP_BLKS) * 256 + t;
        int d = ei[EREAL + e];
        epos[e] = atomicAdd(&deg[d], 1);
    } else {
        int idx = (b - PREP_BLKS - DEG_BLKS) * 256 + t;
        if (idx < HC * IN_CH) {
            int n = idx / IN_CH, k = idx % IN_CH;
            w1t[idx] = f2bf(w1[(size_t)k * HC + n]);
        } else {
            int j = idx - HC * IN_CH;
            int n = j / HC, k = j % HC;
            w2t[j] = f2bf(w2[(size_t)k * HC + n]);
        }
    }
}

// ---- scan degrees -> rowptr; write self-loop at slot 0 of each segment ----
__global__ __launch_bounds__(1024) void k_scan(const int* __restrict__ deg, int* __restrict__ rowptr,
                                               int* __restrict__ csr) {
    __shared__ int sd[1024];
    int t = threadIdx.x;
    int base = t * 32;
    int loc[32];
    int s = 0;
    for (int j = 0; j < 32; j++) { int d = deg[base + j] + 1; loc[j] = d; s += d; }
    sd[t] = s; __syncthreads();
    for (int o = 1; o < 1024; o <<= 1) {
        int v = (t >= o) ? sd[t - o] : 0;
        __syncthreads();
        sd[t] += v;
        __syncthreads();
    }
    int run = sd[t] - s;  // exclusive prefix
    for (int j = 0; j < 32; j++) {
        rowptr[base + j] = run;
        csr[run] = base + j;   // self-loop at slot 0
        run += loc[j];
    }
    if (t == 1023) rowptr[NTN] = run;
}

// ---- atomic-free CSR fill using precomputed slots ----
__global__ void k_fill(const int* __restrict__ ei, const int* __restrict__ epos,
                       const int* __restrict__ rowptr, int* __restrict__ csr) {
    int e = blockIdx.x * 256 + threadIdx.x;
    if (e >= EREAL) return;
    int s = ei[e], d = ei[EREAL + e];
    csr[rowptr[d] + 1 + epos[e]] = s;
}

// ---- bf16 MFMA GEMM: C[M,256] = A[M,K] @ Bt[256,K]^T, fused att head-dots ----
__global__ __launch_bounds__(256) void k_gemm_mfma(
    const unsigned short* __restrict__ A, const unsigned short* __restrict__ Bt, int K,
    const float* __restrict__ attS, const float* __restrict__ attD,
    unsigned short* __restrict__ Cout, float* __restrict__ aS, float* __restrict__ aD) {
    __shared__ unsigned short As[128][72];
    __shared__ unsigned short Bs[64][72];
    const int t = threadIdx.x;
    const int lane = t & 63, wave = t >> 6;
    const int quad = lane >> 4, l16 = lane & 15;
    const int bx = blockIdx.x, by = blockIdx.y;
    const int arow = t >> 1, acol = (t & 1) * 32;
    const int brow = t >> 2, bcol = (t & 3) * 16;
    const unsigned short* Ag = A + (size_t)(by * 128 + arow) * K + acol;
    const unsigned short* Bg = Bt + (size_t)(bx * 64 + brow) * K + bcol;
    f32x4 acc[2][4] = {};
    for (int k0 = 0; k0 < K; k0 += 64) {
        uint4 a0 = *(const uint4*)(Ag + k0);
        uint4 a1 = *(const uint4*)(Ag + k0 + 8);
        uint4 a2 = *(const uint4*)(Ag + k0 + 16);
        uint4 a3 = *(const uint4*)(Ag + k0 + 24);
        uint4 b0 = *(const uint4*)(Bg + k0);
        uint4 b1 = *(const uint4*)(Bg + k0 + 8);
        __syncthreads();
        *(uint4*)&As[arow][acol +  0] = a0;
        *(uint4*)&As[arow][acol +  8] = a1;
        *(uint4*)&As[arow][acol + 16] = a2;
        *(uint4*)&As[arow][acol + 24] = a3;
        *(uint4*)&Bs[brow][bcol +  0] = b0;
        *(uint4*)&Bs[brow][bcol +  8] = b1;
        __syncthreads();
#pragma unroll
        for (int kc = 0; kc < 64; kc += 32) {
            bf16x8 af[2], bfr[4];
#pragma unroll
            for (int mt = 0; mt < 2; mt++)
                af[mt] = *(const bf16x8*)&As[wave * 32 + mt * 16 + l16][kc + quad * 8];
#pragma unroll
            for (int nt = 0; nt < 4; nt++)
                bfr[nt] = *(const bf16x8*)&Bs[nt * 16 + l16][kc + quad * 8];
#pragma unroll
            for (int mt = 0; mt < 2; mt++)
#pragma unroll
                for (int nt = 0; nt < 4; nt++)
                    acc[mt][nt] = __builtin_amdgcn_mfma_f32_16x16x32_bf16(af[mt], bfr[nt], acc[mt][nt], 0, 0, 0);
        }
    }
    float as_l[4], ad_l[4];
#pragma unroll
    for (int nt = 0; nt < 4; nt++) {
        int gcol = bx * 64 + nt * 16 + l16;
        as_l[nt] = attS[gcol];
        ad_l[nt] = attD[gcol];
    }
#pragma unroll
    for (int mt = 0; mt < 2; mt++) {
#pragma unroll
        for (int reg = 0; reg < 4; reg++) {
            int grow = by * 128 + wave * 32 + mt * 16 + quad * 4 + reg;
            float ps = 0.f, pd = 0.f;
#pragma unroll
            for (int nt = 0; nt < 4; nt++) {
                float v = acc[mt][nt][reg];
                Cout[(size_t)grow * HC + bx * 64 + nt * 16 + l16] = f2bf(v);
                ps += v * as_l[nt];
                pd += v * ad_l[nt];
            }
            for (int o = 8; o; o >>= 1) { ps += __shfl_xor(ps, o); pd += __shfl_xor(pd, o); }
            if (l16 == 0) { aS[grow * 4 + bx] = ps; aD[grow * 4 + bx] = pd; }
        }
    }
}

// ---- attention aggregate: 2 nodes/block, 2 waves/node, ea cached in LDS, unroll-4 ----
__global__ __launch_bounds__(256) void k_agg(
    const unsigned short* __restrict__ xw, const float* __restrict__ aS, const float* __restrict__ aD,
    const int* __restrict__ rowptr, const int* __restrict__ csr,
    const float* __restrict__ bias, const float* __restrict__ poolw, const float* __restrict__ poolb,
    unsigned short* __restrict__ hout, float* __restrict__ xpre) {
    __shared__ float ea_s[2][CAP][4];
    __shared__ float part[2][2][256];
    __shared__ float lpart[2][2][4];
    int t = threadIdx.x;
    int wave = t >> 6, lane = t & 63;
    int nd = wave >> 1, half = wave & 1;
    int n = blockIdx.x * 2 + nd;
    int beg = rowptr[n], end = rowptr[n + 1];
    int deg = end - beg;
    int mid = beg + ((deg + 1) >> 1);
    int wbeg = half ? mid : beg;
    int wend = half ? end : mid;
    float4 ad4 = *(const float4*)(aD + n * 4);
    float l0 = 0.f, l1 = 0.f, l2 = 0.f, l3 = 0.f;
    for (int i = wbeg + lane; i < wend; i += 64) {
        int s = csr[i];
        float4 as4 = *(const float4*)(aS + s * 4);
        float a0 = as4.x + ad4.x; a0 = a0 > 0.f ? a0 : 0.2f * a0; float e0 = __expf(a0);
        float a1 = as4.y + ad4.y; a1 = a1 > 0.f ? a1 : 0.2f * a1; float e1 = __expf(a1);
        float a2 = as4.z + ad4.z; a2 = a2 > 0.f ? a2 : 0.2f * a2; float e2 = __expf(a2);
        float a3 = as4.w + ad4.w; a3 = a3 > 0.f ? a3 : 0.2f * a3; float e3 = __expf(a3);
        l0 += e0; l1 += e1; l2 += e2; l3 += e3;
        int j = i - beg;
        if (j < CAP) {
            float4 e4; e4.x = e0; e4.y = e1; e4.z = e2; e4.w = e3;
            *(float4*)&ea_s[nd][j][0] = e4;
        }
    }
    l0 = wave_sum(l0); l1 = wave_sum(l1); l2 = wave_sum(l2); l3 = wave_sum(l3);
    if (lane == 0) {
        lpart[nd][half][0] = l0; lpart[nd][half][1] = l1;
        lpart[nd][half][2] = l2; lpart[nd][half][3] = l3;
    }
    __syncthreads();
    int hd = lane >> 4;
    float ilh = 1.0f / (lpart[nd][0][hd] + lpart[nd][1][hd] + 1e-16f);
    float adh = (hd == 0) ? ad4.x : (hd == 1) ? ad4.y : (hd == 2) ? ad4.z : ad4.w;
    float4 a0v = {0.f, 0.f, 0.f, 0.f}, a1v = {0.f, 0.f, 0.f, 0.f};
    float4 a2v = {0.f, 0.f, 0.f, 0.f}, a3v = {0.f, 0.f, 0.f, 0.f};
    if (deg <= CAP) {
        int i = wbeg;
        for (; i + 4 <= wend; i += 4) {
            int s0 = csr[i], s1 = csr[i + 1], s2 = csr[i + 2], s3 = csr[i + 3];
            float e0 = ea_s[nd][i - beg][hd];
            float e1 = ea_s[nd][i - beg + 1][hd];
            float e2 = ea_s[nd][i - beg + 2][hd];
            float e3 = ea_s[nd][i - beg + 3][hd];
            ushort4 v0 = *(const ushort4*)(xw + (size_t)s0 * HC + lane * 4);
            ushort4 v1 = *(const ushort4*)(xw + (size_t)s1 * HC + lane * 4);
            ushort4 v2 = *(const ushort4*)(xw + (size_t)s2 * HC + lane * 4);
            ushort4 v3 = *(const ushort4*)(xw + (size_t)s3 * HC + lane * 4);
            a0v.x += bf2f(v0.x) * e0; a0v.y += bf2f(v0.y) * e0; a0v.z += bf2f(v0.z) * e0; a0v.w += bf2f(v0.w) * e0;
            a1v.x += bf2f(v1.x) * e1; a1v.y += bf2f(v1.y) * e1; a1v.z += bf2f(v1.z) * e1; a1v.w += bf2f(v1.w) * e1;
            a2v.x += bf2f(v2.x) * e2; a2v.y += bf2f(v2.y) * e2; a2v.z += bf2f(v2.z) * e2; a2v.w += bf2f(v2.w) * e2;
            a3v.x += bf2f(v3.x) * e3; a3v.y += bf2f(v3.y) * e3; a3v.z += bf2f(v3.z) * e3; a3v.w += bf2f(v3.w) * e3;
        }
        for (; i < wend; i++) {
            int s0 = csr[i];
            float e0 = ea_s[nd][i - beg][hd];
            ushort4 v0 = *(const ushort4*)(xw + (size_t)s0 * HC + lane * 4);
            a0v.x += bf2f(v0.x) * e0; a0v.y += bf2f(v0.y) * e0; a0v.z += bf2f(v0.z) * e0; a0v.w += bf2f(v0.w) * e0;
        }
    } else {
        for (int i = wbeg; i < wend; i++) {
            int s = csr[i];
            float a = aS[s * 4 + hd] + adh;
            a = a > 0.f ? a : 0.2f * a;
            float e = __expf(a);
            ushort4 v = *(const ushort4*)(xw + (size_t)s * HC + lane * 4);
            a0v.x += bf2f(v.x) * e; a0v.y += bf2f(v.y) * e;
            a0v.z += bf2f(v.z) * e; a0v.w += bf2f(v.w) * e;
        }
    }
    float4 acc;
    acc.x = (a0v.x + a1v.x) + (a2v.x + a3v.x);
    acc.y = (a0v.y + a1v.y) + (a2v.y + a3v.y);
    acc.z = (a0v.z + a1v.z) + (a2v.z + a3v.z);
    acc.w = (a0v.w + a1v.w) + (a2v.w + a3v.w);
    *(float4*)&part[nd][half][lane * 4] = acc;
    __syncthreads();
    if (half == 0) {
        float4 p0 = *(const float4*)&part[nd][0][lane * 4];
        float4 p1 = *(const float4*)&part[nd][1][lane * 4];
        float4 bv = *(const float4*)(bias + lane * 4);
        float4 r;
        r.x = (p0.x + p1.x) * ilh + bv.x; r.x = r.x > 0.f ? r.x : expm1f(r.x);
        r.y = (p0.y + p1.y) * ilh + bv.y; r.y = r.y > 0.f ? r.y : expm1f(r.y);
        r.z = (p0.z + p1.z) * ilh + bv.z; r.z = r.z > 0.f ? r.z : expm1f(r.z);
        r.w = (p0.w + p1.w) * ilh + bv.w; r.w = r.w > 0.f ? r.w : expm1f(r.w);
        if (hout) {
            ushort4 o;
            o.x = f2bf(r.x); o.y = f2bf(r.y); o.z = f2bf(r.z); o.w = f2bf(r.w);
            *(ushort4*)(hout + (size_t)n * HC + lane * 4) = o;
        }
        float4 pw = *(const float4*)(poolw + lane * 4);
        float p = r.x * pw.x + r.y * pw.y + r.z * pw.z + r.w * pw.w;
        p = wave_sum(p);
        if (lane == 0) xpre[n] = p + poolb[0];
    }
}

// ---- LayerNorm over rows of [B, NN]; dst offset to feat column block ----
__global__ __launch_bounds__(256) void k_ln(const float* __restrict__ src, const float* __restrict__ lw,
                                            const float* __restrict__ lb, float* __restrict__ dst) {
    __shared__ float r0[256], r1[256];
    int row = blockIdx.x, t = threadIdx.x;
    float v[8];
    float s = 0.f, s2 = 0.f;
#pragma unroll
    for (int j = 0; j < 8; j++) {
        float x = src[(size_t)row * NN + t + j * 256];
        v[j] = x; s += x; s2 += x * x;
    }
    r0[t] = s; r1[t] = s2; __syncthreads();
    for (int o = 128; o; o >>= 1) {
        if (t < o) { r0[t] += r0[t + o]; r1[t] += r1[t + o]; }
        __syncthreads();
    }
    float mu = r0[0] * (1.0f / NN);
    float var = r1[0] * (1.0f / NN) - mu * mu;
    float rs = rsqrtf(var + 1e-5f);
#pragma unroll
    for (int j = 0; j < 8; j++) {
        int idx = t + j * 256;
        dst[(size_t)row * (3 * NN) + idx] = (v[j] - mu) * rs * lw[idx] + lb[idx];
    }
}

// ---- split-K FC stage 1 ----
__global__ __launch_bounds__(256) void k_fc_splitk(const float* __restrict__ In, const float* __restrict__ W,
                                                   float* __restrict__ partial, int K, int Nc, int KC) {
    int col = blockIdx.x * 256 + threadIdx.x;
    int k0 = blockIdx.y * KC;
    float acc[16] = {};
    if (col < Nc) {
        const float* wp = W + (size_t)k0 * Nc + col;
#pragma unroll 4
        for (int kk = 0; kk < KC; kk++) {
            float w = wp[(size_t)kk * Nc];
#pragma unroll
            for (int r = 0; r < 16; r++) acc[r] += In[r * K + k0 + kk] * w;
        }
        float* pp = partial + ((size_t)blockIdx.y * 16) * Nc + col;
#pragma unroll
        for (int r = 0; r < 16; r++) pp[(size_t)r * Nc] = acc[r];
    }
}

// ---- split-K FC stage 2 ----
__global__ __launch_bounds__(256) void k_fc_reduce(const float* __restrict__ partial, const float* __restrict__ bias,
                                                   float* __restrict__ Out, int Nc, int KS, int doElu) {
    int idx = blockIdx.x * 256 + threadIdx.x;
    if (idx >= 16 * Nc) return;
    int col = idx % Nc;
    float s = bias[col];
    for (int ks = 0; ks < KS; ks++) s += partial[(size_t)ks * 16 * Nc + idx];
    if (doElu) s = s > 0.f ? s : expm1f(s);
    Out[idx] = s;
}

// ---- last layer: Out[16,2] = In[16,128] @ W[128,2] + b ----
__global__ __launch_bounds__(256) void k_last(const float* __restrict__ In, const float* __restrict__ W,
                                              const float* __restrict__ b, float* __restrict__ Out) {
    int t = threadIdx.x;
    int r = t >> 4, c = (t >> 3) & 1, ksub = t & 7;
    float s = 0.f;
    for (int k = ksub; k < OMIC; k += 8) s += In[r * OMIC + k] * W[k * OUTD + c];
    for (int o = 1; o < 8; o <<= 1) s += __shfl_xor(s, o);
    if (ksub == 0) Out[r * OUTD + c] = s + b[c];
}

extern "C" void kernel_launch(void* const* d_in, const int* in_sizes, int n_in,
                              void* d_out, int out_size, void* d_ws, size_t ws_size,
                              hipStream_t stream) {
    (void)in_sizes; (void)n_in; (void)out_size; (void)ws_size;
    const float* x        = (const float*)d_in[0];
    const int*   ei       = (const int*)d_in[1];
    const float* w1       = (const float*)d_in[2];
    const float* att_src1 = (const float*)d_in[3];
    const float* att_dst1 = (const float*)d_in[4];
    const float* bias1    = (const float*)d_in[5];
    const float* pool1_w  = (const float*)d_in[6];
    const float* pool1_b  = (const float*)d_in[7];
    const float* w2       = (const float*)d_in[8];
    const float* att_src2 = (const float*)d_in[9];
    const float* att_dst2 = (const float*)d_in[10];
    const float* bias2    = (const float*)d_in[11];
    const float* pool2_w  = (const float*)d_in[12];
    const float* pool2_b  = (const float*)d_in[13];
    const float* ln_w     = (const float*)d_in[14];
    const float* ln_b     = (const float*)d_in[15];
    const float* enc0_w   = (const float*)d_in[16];
    const float* enc0_b   = (const float*)d_in[17];
    const float* enc1_w   = (const float*)d_in[18];
    const float* enc1_b   = (const float*)d_in[19];
    const float* enc2_w   = (const float*)d_in[20];
    const float* enc2_b   = (const float*)d_in[21];
    const float* last_w   = (const float*)d_in[22];
    const float* last_b   = (const float*)d_in[23];
    float* out = (float*)d_out;

    char* p = (char*)d_ws;
    auto alloc = [&](size_t bytes) -> void* {
        void* r = (void*)p;
        p += (bytes + 255) & ~(size_t)255;
        return r;
    };
    unsigned short* xwb  = (unsigned short*)alloc((size_t)NTN * HC * 2);
    unsigned short* hb   = (unsigned short*)alloc((size_t)NTN * HC * 2);
    unsigned short* xb   = (unsigned short*)alloc((size_t)NTN * IN_CH * 2);
    unsigned short* w1t  = (unsigned short*)alloc((size_t)HC * IN_CH * 2);
    unsigned short* w2t  = (unsigned short*)alloc((size_t)HC * HC * 2);
    float* a_src  = (float*)alloc((size_t)NTN * 4 * 4);
    float* a_dst  = (float*)alloc((size_t)NTN * 4 * 4);
    float* xmean  = (float*)alloc((size_t)NTN * 4);
    float* x1pre  = (float*)alloc((size_t)NTN * 4);
    float* x2pre  = (float*)alloc((size_t)NTN * 4);
    float* feat   = (float*)alloc((size_t)BB * 3 * NN * 4);
    float* e0     = (float*)alloc((size_t)BB * FC0 * 4);
    float* e1     = (float*)alloc((size_t)BB * FC1 * 4);
    float* e2     = (float*)alloc((size_t)BB * OMIC * 4);
    float* partial= (float*)alloc((size_t)96 * 16 * FC0 * 4);
    int*   deg    = (int*)alloc((size_t)NTN * 4);
    int*   rowptr = (int*)alloc((size_t)(NTN + 1) * 4);
    int*   epos   = (int*)alloc((size_t)EREAL * 4);
    int*   csr    = (int*)alloc((size_t)ETOT * 4);

    hipMemsetAsync(deg, 0, (size_t)NTN * 4, stream);

    k_pre<<<PREP_BLKS + DEG_BLKS + CASTW_BLKS, 256, 0, stream>>>(
        x, xb, xmean, ei, deg, epos, w1, w2, w1t, w2t);
    k_scan<<<1, 1024, 0, stream>>>(deg, rowptr, csr);
    k_fill<<<(EREAL + 255) / 256, 256, 0, stream>>>(ei, epos, rowptr, csr);

    // GAT layer 1
    k_gemm_mfma<<<dim3(4, NTN / 128), 256, 0, stream>>>(xb, w1t, IN_CH, att_src1, att_dst1, xwb, a_src, a_dst);
    k_ln<<<BB, 256, 0, stream>>>(xmean, ln_w, ln_b, feat + 0);
    k_agg<<<NTN / 2, 256, 0, stream>>>(xwb, a_src, a_dst, rowptr, csr, bias1, pool1_w, pool1_b, hb, x1pre);
    k_ln<<<BB, 256, 0, stream>>>(x1pre, ln_w, ln_b, feat + NN);

    // GAT layer 2
    k_gemm_mfma<<<dim3(4, NTN / 128), 256, 0, stream>>>(hb, w2t, HC, att_src2, att_dst2, xwb, a_src, a_dst);
    k_agg<<<NTN / 2, 256, 0, stream>>>(xwb, a_src, a_dst, rowptr, csr, bias2, pool2_w, pool2_b, (unsigned short*)nullptr, x2pre);
    k_ln<<<BB, 256, 0, stream>>>(x2pre, ln_w, ln_b, feat + 2 * NN);

    // encoder MLP
    k_fc_splitk<<<dim3(4, 96), 256, 0, stream>>>(feat, enc0_w, partial, 3 * NN, FC0, 64);
    k_fc_reduce<<<(16 * FC0 + 255) / 256, 256, 0, stream>>>(partial, enc0_b, e0, FC0, 96, 1);
    k_fc_splitk<<<dim3(2, 32), 256, 0, stream>>>(e0, enc1_w, partial, FC0, FC1, 32);
    k_fc_reduce<<<(16 * FC1 + 255) / 256, 256, 0, stream>>>(partial, enc1_b, e1, FC1, 32, 1);
    k_fc_splitk<<<dim3(1, 32), 256, 0, stream>>>(e1, enc2_w, partial, FC1, OMIC, 16);
    k_fc_reduce<<<(16 * OMIC + 255) / 256, 256, 0, stream>>>(partial, enc2_b, e2, OMIC, 32, 1);
    k_last<<<1, 256, 0, stream>>>(e2, last_w, last_b, out);
}